// Round 1
// baseline (1252.049 us; speedup 1.0000x reference)
//
#include <hip/hip_runtime.h>
#include <stdint.h>

// Sizes (fixed by problem)
#define NN 100000
#define NE 1600000
#define NG 256

__device__ inline uint32_t f2bf(float f){
    uint32_t u = __float_as_uint(f);
    return (u + 0x7FFFu + ((u >> 16) & 1u)) >> 16;   // RNE bf16
}
__device__ inline float2 unpk(uint32_t u){
    float2 r;
    r.x = __uint_as_float(u << 16);
    r.y = __uint_as_float(u & 0xFFFF0000u);
    return r;
}

// ---------------- embedding + max_norm ----------------
__global__ __launch_bounds__(256) void k_embed(const int* __restrict__ x,
                                               const float* __restrict__ emb,
                                               float* __restrict__ hout){
    int w = threadIdx.x >> 6, l = threadIdx.x & 63;
    int n = blockIdx.x * 4 + w;                       // N divisible by 4
    int r = x[n];
    const float2* e2 = (const float2*)emb;
    float2 v = e2[(size_t)r * 64 + l];
    float ss = v.x * v.x + v.y * v.y;
    #pragma unroll
    for (int off = 32; off; off >>= 1) ss += __shfl_xor(ss, off, 64);
    float sc = fminf(1.f, 1.f / (sqrtf(ss) + 1e-7f));
    ((float2*)hout)[(size_t)n * 64 + l] = make_float2(v.x * sc, v.y * sc);
}

// ---------------- weight pre-pack: [k][l] -> {bf16x2 rel(2l,2l+1), bf16x2 root} ----------------
__global__ __launch_bounds__(256) void k_pack(const float* __restrict__ wrel,
                                              const float* __restrict__ wroot,
                                              uint32_t* __restrict__ wpk){
    int id = blockIdx.x * 256 + threadIdx.x;          // 8192 total
    int k = id >> 6, l = id & 63;
    uint32_t a0 = f2bf(wrel [(2 * l) * 128 + k]);
    uint32_t a1 = f2bf(wrel [(2 * l + 1) * 128 + k]);
    uint32_t b0 = f2bf(wroot[(2 * l) * 128 + k]);
    uint32_t b1 = f2bf(wroot[(2 * l + 1) * 128 + k]);
    wpk[id * 2 + 0] = a0 | (a1 << 16);
    wpk[id * 2 + 1] = b0 | (b1 << 16);
}

// ---------------- CSR build ----------------
__global__ __launch_bounds__(256) void k_count(const int* __restrict__ dst, int* __restrict__ deg, int E){
    int e = blockIdx.x * 256 + threadIdx.x;
    if (e < E) atomicAdd(&deg[dst[e]], 1);
}

__global__ __launch_bounds__(256) void k_scan_blocks(const int* __restrict__ deg, int* __restrict__ bsum, int N){
    __shared__ int red[256];
    int t = threadIdx.x;
    int base = blockIdx.x * 1024 + t * 4;
    int s = 0;
    #pragma unroll
    for (int i = 0; i < 4; ++i){ int idx = base + i; if (idx < N) s += deg[idx]; }
    red[t] = s; __syncthreads();
    for (int off = 128; off > 0; off >>= 1){
        if (t < off) red[t] += red[t + off];
        __syncthreads();
    }
    if (t == 0) bsum[blockIdx.x] = red[0];
}

__global__ void k_scan_top(const int* __restrict__ bsum, int* __restrict__ boff,
                           int* __restrict__ ptr, int nblocks, int N, int E){
    int l = threadIdx.x;                               // 64 threads
    int v0 = (l < nblocks) ? bsum[l] : 0;
    int i1 = 64 + l;
    int v1 = (i1 < nblocks) ? bsum[i1] : 0;
    int s0 = v0;
    #pragma unroll
    for (int off = 1; off < 64; off <<= 1){ int u = __shfl_up(s0, off, 64); if (l >= off) s0 += u; }
    int tot0 = __shfl(s0, 63, 64);
    int s1 = v1;
    #pragma unroll
    for (int off = 1; off < 64; off <<= 1){ int u = __shfl_up(s1, off, 64); if (l >= off) s1 += u; }
    s1 += tot0;
    if (l  < nblocks) boff[l]  = s0 - v0;
    if (i1 < nblocks) boff[i1] = s1 - v1;
    if (l == 0) ptr[N] = E;
}

__global__ __launch_bounds__(256) void k_scan_write(const int* __restrict__ deg,
                                                    const int* __restrict__ boff,
                                                    int* __restrict__ ptr, int N){
    __shared__ int lds[256];
    int t = threadIdx.x;
    int base = blockIdx.x * 1024 + t * 4;
    int d[4]; int s = 0;
    #pragma unroll
    for (int i = 0; i < 4; ++i){ d[i] = (base + i < N) ? deg[base + i] : 0; s += d[i]; }
    lds[t] = s; __syncthreads();
    for (int off = 1; off < 256; off <<= 1){
        int v = (t >= off) ? lds[t - off] : 0;
        __syncthreads();
        lds[t] += v;
        __syncthreads();
    }
    int acc = lds[t] - s + boff[blockIdx.x];
    #pragma unroll
    for (int i = 0; i < 4; ++i){ if (base + i < N) ptr[base + i] = acc; acc += d[i]; }
}

__global__ __launch_bounds__(256) void k_fill(const int* __restrict__ src, const int* __restrict__ dst,
                                              const float* __restrict__ ew,
                                              const int* __restrict__ ptr, int* __restrict__ fill,
                                              int* __restrict__ csrc, float* __restrict__ cw, int E){
    int e = blockIdx.x * 256 + threadIdx.x;
    if (e < E){
        int d = dst[e];
        int pos = ptr[d] + atomicAdd(&fill[d], 1);
        csrc[pos] = src[e];
        cw[pos] = ew[e];
    }
}

// ---------------- graph boundaries (batch is sorted) ----------------
__global__ __launch_bounds__(256) void k_gstart(const int* __restrict__ batch, int* __restrict__ gstart, int N){
    int i = blockIdx.x * 256 + threadIdx.x;
    if (i > N) return;
    int bprev = (i == 0) ? -1 : batch[i - 1];
    int bcur  = (i == N) ? NG : batch[i];
    for (int g = bprev + 1; g <= bcur; ++g) gstart[g] = i;
}

// ---------------- fused GraphConv: agg (CSR gather) + dual GEMM + bias + relu ----------------
// block = 256 threads (4 waves), 16 nodes/block (wave handles 4 sequential nodes)
__global__ __launch_bounds__(256) void k_conv(const float* __restrict__ hin,
                                              float* __restrict__ hout,
                                              const int* __restrict__ ptr,
                                              const int* __restrict__ csrc,
                                              const float* __restrict__ cw,
                                              const uint32_t* __restrict__ wpk,
                                              const float* __restrict__ bias){
    __shared__ float2 ldsA[16][64];   // agg rows   (8 KB)
    __shared__ float2 ldsH[16][64];   // own rows   (8 KB)
    __shared__ uint2  ldsW[64 * 64];  // weight k-chunk (32 KB)
    int t = threadIdx.x, w = t >> 6, l = t & 63;
    int nb = blockIdx.x * 16;
    const float2* hin2 = (const float2*)hin;

    // Phase A: gather-aggregate (no atomics)
    #pragma unroll
    for (int tt = 0; tt < 4; ++tt){
        int nn = w * 4 + tt;
        int n = nb + nn;
        float2 agg = {0.f, 0.f};
        int p0 = ptr[n], p1 = ptr[n + 1];
        for (int e = p0; e < p1; ++e){
            int s = csrc[e];
            float we = cw[e];
            float2 v = hin2[(size_t)s * 64 + l];
            agg.x += we * v.x;
            agg.y += we * v.y;
        }
        ldsA[nn][l] = agg;
        ldsH[nn][l] = hin2[(size_t)n * 64 + l];
    }
    __syncthreads();

    // Phase B: out[n][2l,2l+1] = relu(bias + agg.Wrel^T + own.Wroot^T), K tiled in 2 chunks
    float2 acc[4] = {{0,0},{0,0},{0,0},{0,0}};
    const uint2* wpk2 = (const uint2*)wpk;
    for (int c = 0; c < 2; ++c){
        for (int i = t; i < 4096; i += 256) ldsW[i] = wpk2[c * 4096 + i];
        __syncthreads();
        for (int k2 = 0; k2 < 64; k2 += 2){
            uint2 wp0 = ldsW[k2 * 64 + l];
            uint2 wp1 = ldsW[(k2 + 1) * 64 + l];
            float2 wr0 = unpk(wp0.x), wo0 = unpk(wp0.y);
            float2 wr1 = unpk(wp1.x), wo1 = unpk(wp1.y);
            int kk = (c * 64 + k2) >> 1;               // float2 index along k
            #pragma unroll
            for (int tt = 0; tt < 4; ++tt){
                float2 aa = ldsA[w * 4 + tt][kk];
                float2 ao = ldsH[w * 4 + tt][kk];
                acc[tt].x += aa.x * wr0.x + ao.x * wo0.x + aa.y * wr1.x + ao.y * wo1.x;
                acc[tt].y += aa.x * wr0.y + ao.x * wo0.y + aa.y * wr1.y + ao.y * wo1.y;
            }
        }
        __syncthreads();
    }
    float2 bv = ((const float2*)bias)[l];
    float2* hout2 = (float2*)hout;
    #pragma unroll
    for (int tt = 0; tt < 4; ++tt){
        int n = nb + w * 4 + tt;
        float2 r;
        r.x = fmaxf(acc[tt].x + bv.x, 0.f);
        r.y = fmaxf(acc[tt].y + bv.y, 0.f);
        hout2[(size_t)n * 64 + l] = r;
    }
}

// ---------------- mean pool per graph ----------------
__global__ __launch_bounds__(128) void k_pool(const float* __restrict__ h,
                                              const int* __restrict__ gstart,
                                              float* __restrict__ pooled){
    int g = blockIdx.x, f = threadIdx.x;               // 128 threads
    int s = gstart[g], e = gstart[g + 1];
    float a0 = 0, a1 = 0, a2 = 0, a3 = 0;
    int i = s;
    for (; i + 3 < e; i += 4){
        a0 += h[(size_t)i * 128 + f];
        a1 += h[(size_t)(i + 1) * 128 + f];
        a2 += h[(size_t)(i + 2) * 128 + f];
        a3 += h[(size_t)(i + 3) * 128 + f];
    }
    for (; i < e; ++i) a0 += h[(size_t)i * 128 + f];
    float sum = (a0 + a1) + (a2 + a3);
    int cnt = e - s;
    pooled[g * 128 + f] = sum / fmaxf((float)cnt, 1.f);
}

// ---------------- classifier + softmax ----------------
__global__ __launch_bounds__(64) void k_cls(const float* __restrict__ pooled,
                                            const float* __restrict__ c1w, const float* __restrict__ c1b,
                                            const float* __restrict__ c2w, const float* __restrict__ c2b,
                                            float* __restrict__ out){
    __shared__ float pl[128];
    __shared__ float z[64];
    __shared__ float logits[2];
    int g = blockIdx.x, t = threadIdx.x;
    pl[t] = pooled[g * 128 + t];
    pl[t + 64] = pooled[g * 128 + 64 + t];
    __syncthreads();
    float acc = c1b[t];
    #pragma unroll 4
    for (int k = 0; k < 128; ++k) acc += pl[k] * c1w[t * 128 + k];
    z[t] = fmaxf(acc, 0.f);
    __syncthreads();
    if (t < 2){
        float a = c2b[t];
        for (int k = 0; k < 64; ++k) a += z[k] * c2w[t * 64 + k];
        logits[t] = a;
    }
    __syncthreads();
    if (t == 0){
        float m = fmaxf(logits[0], logits[1]);
        float e0 = expf(logits[0] - m), e1 = expf(logits[1] - m);
        float s = e0 + e1;
        out[g * 2 + 0] = e0 / s;
        out[g * 2 + 1] = e1 / s;
    }
}

extern "C" void kernel_launch(void* const* d_in, const int* in_sizes, int n_in,
                              void* d_out, int out_size, void* d_ws, size_t ws_size,
                              hipStream_t stream) {
    const int*   x      = (const int*)  d_in[0];
    const int*   eidx   = (const int*)  d_in[1];
    const float* ew     = (const float*)d_in[2];
    const int*   batch  = (const int*)  d_in[3];
    const float* emb    = (const float*)d_in[4];
    const float* w1rel  = (const float*)d_in[5];
    const float* b1     = (const float*)d_in[6];
    const float* w1root = (const float*)d_in[7];
    const float* w2rel  = (const float*)d_in[8];
    const float* b2     = (const float*)d_in[9];
    const float* w2root = (const float*)d_in[10];
    const float* c1w    = (const float*)d_in[11];
    const float* c1b    = (const float*)d_in[12];
    const float* c2w    = (const float*)d_in[13];
    const float* c2b    = (const float*)d_in[14];
    float* out = (float*)d_out;

    const int N = NN;                 // 100000
    const int E = NE;                 // 1600000

    char* p = (char*)d_ws;
    auto alloc = [&](size_t bytes) -> void* {
        void* r = (void*)p;
        p += (bytes + 255) & ~(size_t)255;
        return r;
    };
    float* hA     = (float*)alloc((size_t)N * 128 * 4);
    float* hB     = (float*)alloc((size_t)N * 128 * 4);
    int*   deg    = (int*)  alloc((size_t)N * 4);
    int*   fill   = (int*)  alloc((size_t)N * 4);
    int*   ptrA   = (int*)  alloc((size_t)(N + 1) * 4);
    int*   bsum   = (int*)  alloc(128 * 4);
    int*   boff   = (int*)  alloc(128 * 4);
    int*   csrc   = (int*)  alloc((size_t)E * 4);
    float* cwv    = (float*)alloc((size_t)E * 4);
    int*   gstart = (int*)  alloc((NG + 1) * 4);
    float* pooled = (float*)alloc((size_t)NG * 128 * 4);
    uint32_t* wpk1 = (uint32_t*)alloc(128 * 64 * 2 * 4);
    uint32_t* wpk2 = (uint32_t*)alloc(128 * 64 * 2 * 4);

    hipMemsetAsync(deg,  0, (size_t)N * 4, stream);
    hipMemsetAsync(fill, 0, (size_t)N * 4, stream);

    k_embed<<<N / 4, 256, 0, stream>>>(x, emb, hA);
    k_pack <<<32, 256, 0, stream>>>(w1rel, w1root, wpk1);
    k_pack <<<32, 256, 0, stream>>>(w2rel, w2root, wpk2);

    const int* esrc = eidx;
    const int* edst = eidx + E;
    k_count<<<(E + 255) / 256, 256, 0, stream>>>(edst, deg, E);
    int nsb = (N + 1023) / 1024;      // 98
    k_scan_blocks<<<nsb, 256, 0, stream>>>(deg, bsum, N);
    k_scan_top<<<1, 64, 0, stream>>>(bsum, boff, ptrA, nsb, N, E);
    k_scan_write<<<nsb, 256, 0, stream>>>(deg, boff, ptrA, N);
    k_fill<<<(E + 255) / 256, 256, 0, stream>>>(esrc, edst, ew, ptrA, fill, csrc, cwv, E);
    k_gstart<<<(N + 1 + 255) / 256, 256, 0, stream>>>(batch, gstart, N);

    k_conv<<<N / 16, 256, 0, stream>>>(hA, hB, ptrA, csrc, cwv, wpk1, b1);
    k_conv<<<N / 16, 256, 0, stream>>>(hB, hA, ptrA, csrc, cwv, wpk2, b2);

    k_pool<<<NG, 128, 0, stream>>>(hA, gstart, pooled);
    k_cls<<<NG, 64, 0, stream>>>(pooled, c1w, c1b, c2w, c2b, out);
}

// Round 2
// 1006.892 us; speedup vs baseline: 1.2435x; 1.2435x over previous
//
#include <hip/hip_runtime.h>
#include <stdint.h>

// Sizes (fixed by problem)
#define NN 100000
#define NE 1600000
#define NG 256

__device__ inline uint32_t f2bf(float f){
    uint32_t u = __float_as_uint(f);
    return (u + 0x7FFFu + ((u >> 16) & 1u)) >> 16;   // RNE bf16
}
__device__ inline float2 unpk(uint32_t u){
    float2 r;
    r.x = __uint_as_float(u << 16);
    r.y = __uint_as_float(u & 0xFFFF0000u);
    return r;
}

// ---------------- embedding + max_norm ----------------
__global__ __launch_bounds__(256) void k_embed(const int* __restrict__ x,
                                               const float* __restrict__ emb,
                                               float* __restrict__ hout){
    int w = threadIdx.x >> 6, l = threadIdx.x & 63;
    int n = blockIdx.x * 4 + w;                       // N divisible by 4
    int r = x[n];
    const float2* e2 = (const float2*)emb;
    float2 v = e2[(size_t)r * 64 + l];
    float ss = v.x * v.x + v.y * v.y;
    #pragma unroll
    for (int off = 32; off; off >>= 1) ss += __shfl_xor(ss, off, 64);
    float sc = fminf(1.f, 1.f / (sqrtf(ss) + 1e-7f));
    ((float2*)hout)[(size_t)n * 64 + l] = make_float2(v.x * sc, v.y * sc);
}

// ---------------- weight pre-pack: [k][l] -> {bf16x2 rel(2l,2l+1), bf16x2 root} ----------------
__global__ __launch_bounds__(256) void k_pack(const float* __restrict__ wrel,
                                              const float* __restrict__ wroot,
                                              uint32_t* __restrict__ wpk){
    int id = blockIdx.x * 256 + threadIdx.x;          // 8192 total
    int k = id >> 6, l = id & 63;
    uint32_t a0 = f2bf(wrel [(2 * l) * 128 + k]);
    uint32_t a1 = f2bf(wrel [(2 * l + 1) * 128 + k]);
    uint32_t b0 = f2bf(wroot[(2 * l) * 128 + k]);
    uint32_t b1 = f2bf(wroot[(2 * l + 1) * 128 + k]);
    wpk[id * 2 + 0] = a0 | (a1 << 16);
    wpk[id * 2 + 1] = b0 | (b1 << 16);
}

// ---------------- CSR build ----------------
__global__ __launch_bounds__(256) void k_count(const int* __restrict__ dst, int* __restrict__ deg, int E){
    int e = blockIdx.x * 256 + threadIdx.x;
    if (e < E) atomicAdd(&deg[dst[e]], 1);
}

__global__ __launch_bounds__(256) void k_scan_blocks(const int* __restrict__ deg, int* __restrict__ bsum, int N){
    __shared__ int red[256];
    int t = threadIdx.x;
    int base = blockIdx.x * 1024 + t * 4;
    int s = 0;
    #pragma unroll
    for (int i = 0; i < 4; ++i){ int idx = base + i; if (idx < N) s += deg[idx]; }
    red[t] = s; __syncthreads();
    for (int off = 128; off > 0; off >>= 1){
        if (t < off) red[t] += red[t + off];
        __syncthreads();
    }
    if (t == 0) bsum[blockIdx.x] = red[0];
}

__global__ void k_scan_top(const int* __restrict__ bsum, int* __restrict__ boff,
                           int* __restrict__ ptr, int nblocks, int N, int E){
    int l = threadIdx.x;                               // 64 threads
    int v0 = (l < nblocks) ? bsum[l] : 0;
    int i1 = 64 + l;
    int v1 = (i1 < nblocks) ? bsum[i1] : 0;
    int s0 = v0;
    #pragma unroll
    for (int off = 1; off < 64; off <<= 1){ int u = __shfl_up(s0, off, 64); if (l >= off) s0 += u; }
    int tot0 = __shfl(s0, 63, 64);
    int s1 = v1;
    #pragma unroll
    for (int off = 1; off < 64; off <<= 1){ int u = __shfl_up(s1, off, 64); if (l >= off) s1 += u; }
    s1 += tot0;
    if (l  < nblocks) boff[l]  = s0 - v0;
    if (i1 < nblocks) boff[i1] = s1 - v1;
    if (l == 0) ptr[N] = E;
}

__global__ __launch_bounds__(256) void k_scan_write(const int* __restrict__ deg,
                                                    const int* __restrict__ boff,
                                                    int* __restrict__ ptr, int N){
    __shared__ int lds[256];
    int t = threadIdx.x;
    int base = blockIdx.x * 1024 + t * 4;
    int d[4]; int s = 0;
    #pragma unroll
    for (int i = 0; i < 4; ++i){ d[i] = (base + i < N) ? deg[base + i] : 0; s += d[i]; }
    lds[t] = s; __syncthreads();
    for (int off = 1; off < 256; off <<= 1){
        int v = (t >= off) ? lds[t - off] : 0;
        __syncthreads();
        lds[t] += v;
        __syncthreads();
    }
    int acc = lds[t] - s + boff[blockIdx.x];
    #pragma unroll
    for (int i = 0; i < 4; ++i){ if (base + i < N) ptr[base + i] = acc; acc += d[i]; }
}

// packed edge record: (src_index, weight_bits)
__global__ __launch_bounds__(256) void k_fill(const int* __restrict__ src, const int* __restrict__ dst,
                                              const float* __restrict__ ew,
                                              const int* __restrict__ ptr, int* __restrict__ fill,
                                              uint2* __restrict__ cse, int E){
    int e = blockIdx.x * 256 + threadIdx.x;
    if (e < E){
        int d = dst[e];
        int pos = ptr[d] + atomicAdd(&fill[d], 1);
        cse[pos] = make_uint2((uint32_t)src[e], __float_as_uint(ew[e]));
    }
}

// ---------------- graph boundaries (batch is sorted) ----------------
__global__ __launch_bounds__(256) void k_gstart(const int* __restrict__ batch, int* __restrict__ gstart, int N){
    int i = blockIdx.x * 256 + threadIdx.x;
    if (i > N) return;
    int bprev = (i == 0) ? -1 : batch[i - 1];
    int bcur  = (i == N) ? NG : batch[i];
    for (int g = bprev + 1; g <= bcur; ++g) gstart[g] = i;
}

// ---------------- fused GraphConv: agg (CSR gather) + dual GEMM + bias + relu ----------------
// block = 256 threads (4 waves), 16 nodes/block (wave handles 4 sequential nodes)
// LDS = 8 + 8 + 16 = 32 KB -> 5 blocks/CU (20 waves/CU)
__global__ __launch_bounds__(256) void k_conv(const float* __restrict__ hin,
                                              float* __restrict__ hout,
                                              const int* __restrict__ ptr,
                                              const uint2* __restrict__ cse,
                                              const uint32_t* __restrict__ wpk,
                                              const float* __restrict__ bias){
    __shared__ float2 ldsA[16][64];    // agg rows   (8 KB)
    __shared__ float2 ldsH[16][64];    // own rows   (8 KB)
    __shared__ uint2  ldsW[32 * 64];   // weight k-chunk (16 KB)
    int t = threadIdx.x, w = t >> 6, l = t & 63;
    int nb = blockIdx.x * 16;
    const float2* hin2 = (const float2*)hin;

    // Phase A: gather-aggregate (no atomics), unrolled x4 for memory-level parallelism
    #pragma unroll
    for (int tt = 0; tt < 4; ++tt){
        int nn = w * 4 + tt;
        int n = nb + nn;
        int p0 = ptr[n], p1 = ptr[n + 1];
        float2 a0 = {0,0}, a1 = {0,0}, a2 = {0,0}, a3 = {0,0};
        int e = p0;
        for (; e + 4 <= p1; e += 4){
            uint2 r0 = cse[e], r1 = cse[e + 1], r2 = cse[e + 2], r3 = cse[e + 3];
            float2 v0 = hin2[(size_t)r0.x * 64 + l];
            float2 v1 = hin2[(size_t)r1.x * 64 + l];
            float2 v2 = hin2[(size_t)r2.x * 64 + l];
            float2 v3 = hin2[(size_t)r3.x * 64 + l];
            float w0 = __uint_as_float(r0.y), w1 = __uint_as_float(r1.y);
            float w2 = __uint_as_float(r2.y), w3 = __uint_as_float(r3.y);
            a0.x += w0 * v0.x; a0.y += w0 * v0.y;
            a1.x += w1 * v1.x; a1.y += w1 * v1.y;
            a2.x += w2 * v2.x; a2.y += w2 * v2.y;
            a3.x += w3 * v3.x; a3.y += w3 * v3.y;
        }
        for (; e < p1; ++e){
            uint2 r0 = cse[e];
            float2 v0 = hin2[(size_t)r0.x * 64 + l];
            float w0 = __uint_as_float(r0.y);
            a0.x += w0 * v0.x; a0.y += w0 * v0.y;
        }
        float2 agg;
        agg.x = (a0.x + a1.x) + (a2.x + a3.x);
        agg.y = (a0.y + a1.y) + (a2.y + a3.y);
        ldsA[nn][l] = agg;
        ldsH[nn][l] = hin2[(size_t)n * 64 + l];
    }
    __syncthreads();

    // Phase B: out[n][2l,2l+1] = relu(bias + agg.Wrel^T + own.Wroot^T), K tiled in 4 chunks of 32
    float2 acc[4] = {{0,0},{0,0},{0,0},{0,0}};
    const uint2* wpk2 = (const uint2*)wpk;
    for (int c = 0; c < 4; ++c){
        for (int i = t; i < 2048; i += 256) ldsW[i] = wpk2[c * 2048 + i];
        __syncthreads();
        for (int k2 = 0; k2 < 32; k2 += 2){
            uint2 wp0 = ldsW[k2 * 64 + l];
            uint2 wp1 = ldsW[(k2 + 1) * 64 + l];
            float2 wr0 = unpk(wp0.x), wo0 = unpk(wp0.y);
            float2 wr1 = unpk(wp1.x), wo1 = unpk(wp1.y);
            int kk = (c * 32 + k2) >> 1;               // float2 index along k
            #pragma unroll
            for (int tt = 0; tt < 4; ++tt){
                float2 aa = ldsA[w * 4 + tt][kk];
                float2 ao = ldsH[w * 4 + tt][kk];
                acc[tt].x += aa.x * wr0.x + ao.x * wo0.x + aa.y * wr1.x + ao.y * wo1.x;
                acc[tt].y += aa.x * wr0.y + ao.x * wo0.y + aa.y * wr1.y + ao.y * wo1.y;
            }
        }
        __syncthreads();
    }
    float2 bv = ((const float2*)bias)[l];
    float2* hout2 = (float2*)hout;
    #pragma unroll
    for (int tt = 0; tt < 4; ++tt){
        int n = nb + w * 4 + tt;
        float2 r;
        r.x = fmaxf(acc[tt].x + bv.x, 0.f);
        r.y = fmaxf(acc[tt].y + bv.y, 0.f);
        hout2[(size_t)n * 64 + l] = r;
    }
}

// ---------------- mean pool per graph ----------------
__global__ __launch_bounds__(128) void k_pool(const float* __restrict__ h,
                                              const int* __restrict__ gstart,
                                              float* __restrict__ pooled){
    int g = blockIdx.x, f = threadIdx.x;               // 128 threads
    int s = gstart[g], e = gstart[g + 1];
    float a0 = 0, a1 = 0, a2 = 0, a3 = 0;
    int i = s;
    for (; i + 3 < e; i += 4){
        a0 += h[(size_t)i * 128 + f];
        a1 += h[(size_t)(i + 1) * 128 + f];
        a2 += h[(size_t)(i + 2) * 128 + f];
        a3 += h[(size_t)(i + 3) * 128 + f];
    }
    for (; i < e; ++i) a0 += h[(size_t)i * 128 + f];
    float sum = (a0 + a1) + (a2 + a3);
    int cnt = e - s;
    pooled[g * 128 + f] = sum / fmaxf((float)cnt, 1.f);
}

// ---------------- classifier + softmax ----------------
__global__ __launch_bounds__(64) void k_cls(const float* __restrict__ pooled,
                                            const float* __restrict__ c1w, const float* __restrict__ c1b,
                                            const float* __restrict__ c2w, const float* __restrict__ c2b,
                                            float* __restrict__ out){
    __shared__ float pl[128];
    __shared__ float z[64];
    __shared__ float logits[2];
    int g = blockIdx.x, t = threadIdx.x;
    pl[t] = pooled[g * 128 + t];
    pl[t + 64] = pooled[g * 128 + 64 + t];
    __syncthreads();
    float acc = c1b[t];
    #pragma unroll 4
    for (int k = 0; k < 128; ++k) acc += pl[k] * c1w[t * 128 + k];
    z[t] = fmaxf(acc, 0.f);
    __syncthreads();
    if (t < 2){
        float a = c2b[t];
        for (int k = 0; k < 64; ++k) a += z[k] * c2w[t * 64 + k];
        logits[t] = a;
    }
    __syncthreads();
    if (t == 0){
        float m = fmaxf(logits[0], logits[1]);
        float e0 = expf(logits[0] - m), e1 = expf(logits[1] - m);
        float s = e0 + e1;
        out[g * 2 + 0] = e0 / s;
        out[g * 2 + 1] = e1 / s;
    }
}

extern "C" void kernel_launch(void* const* d_in, const int* in_sizes, int n_in,
                              void* d_out, int out_size, void* d_ws, size_t ws_size,
                              hipStream_t stream) {
    const int*   x      = (const int*)  d_in[0];
    const int*   eidx   = (const int*)  d_in[1];
    const float* ew     = (const float*)d_in[2];
    const int*   batch  = (const int*)  d_in[3];
    const float* emb    = (const float*)d_in[4];
    const float* w1rel  = (const float*)d_in[5];
    const float* b1     = (const float*)d_in[6];
    const float* w1root = (const float*)d_in[7];
    const float* w2rel  = (const float*)d_in[8];
    const float* b2     = (const float*)d_in[9];
    const float* w2root = (const float*)d_in[10];
    const float* c1w    = (const float*)d_in[11];
    const float* c1b    = (const float*)d_in[12];
    const float* c2w    = (const float*)d_in[13];
    const float* c2b    = (const float*)d_in[14];
    float* out = (float*)d_out;

    const int N = NN;                 // 100000
    const int E = NE;                 // 1600000

    char* p = (char*)d_ws;
    auto alloc = [&](size_t bytes) -> void* {
        void* r = (void*)p;
        p += (bytes + 255) & ~(size_t)255;
        return r;
    };
    float* hA     = (float*)alloc((size_t)N * 128 * 4);
    float* hB     = (float*)alloc((size_t)N * 128 * 4);
    int*   deg    = (int*)  alloc((size_t)N * 4);
    int*   fill   = (int*)  alloc((size_t)N * 4);
    int*   ptrA   = (int*)  alloc((size_t)(N + 1) * 4);
    int*   bsum   = (int*)  alloc(128 * 4);
    int*   boff   = (int*)  alloc(128 * 4);
    uint2* cse    = (uint2*)alloc((size_t)E * 8);
    int*   gstart = (int*)  alloc((NG + 1) * 4);
    float* pooled = (float*)alloc((size_t)NG * 128 * 4);
    uint32_t* wpk1 = (uint32_t*)alloc(128 * 64 * 2 * 4);
    uint32_t* wpk2 = (uint32_t*)alloc(128 * 64 * 2 * 4);

    hipMemsetAsync(deg,  0, (size_t)N * 4, stream);
    hipMemsetAsync(fill, 0, (size_t)N * 4, stream);

    k_embed<<<N / 4, 256, 0, stream>>>(x, emb, hA);
    k_pack <<<32, 256, 0, stream>>>(w1rel, w1root, wpk1);
    k_pack <<<32, 256, 0, stream>>>(w2rel, w2root, wpk2);

    const int* esrc = eidx;
    const int* edst = eidx + E;
    k_count<<<(E + 255) / 256, 256, 0, stream>>>(edst, deg, E);
    int nsb = (N + 1023) / 1024;      // 98
    k_scan_blocks<<<nsb, 256, 0, stream>>>(deg, bsum, N);
    k_scan_top<<<1, 64, 0, stream>>>(bsum, boff, ptrA, nsb, N, E);
    k_scan_write<<<nsb, 256, 0, stream>>>(deg, boff, ptrA, N);
    k_fill<<<(E + 255) / 256, 256, 0, stream>>>(esrc, edst, ew, ptrA, fill, cse, E);
    k_gstart<<<(N + 1 + 255) / 256, 256, 0, stream>>>(batch, gstart, N);

    k_conv<<<N / 16, 256, 0, stream>>>(hA, hB, ptrA, cse, wpk1, b1);
    k_conv<<<N / 16, 256, 0, stream>>>(hB, hA, ptrA, cse, wpk2, b2);

    k_pool<<<NG, 128, 0, stream>>>(hA, gstart, pooled);
    k_cls<<<NG, 64, 0, stream>>>(pooled, c1w, c1b, c2w, c2b, out);
}

// Round 3
// 501.669 us; speedup vs baseline: 2.4958x; 2.0071x over previous
//
#include <hip/hip_runtime.h>
#include <stdint.h>

// Sizes (fixed by problem)
#define NN 100000
#define NE 1600000
#define NG 256

typedef __attribute__((ext_vector_type(8))) short bf16x8;   // 8 bf16 = 4 VGPR
typedef __attribute__((ext_vector_type(4))) float f32x4;

__device__ inline uint32_t f2bf(float f){
    uint32_t u = __float_as_uint(f);
    return (u + 0x7FFFu + ((u >> 16) & 1u)) >> 16;   // RNE bf16
}
__device__ inline float bflo(uint32_t u){ return __uint_as_float(u << 16); }
__device__ inline float bfhi(uint32_t u){ return __uint_as_float(u & 0xFFFF0000u); }
__device__ inline float bf1(short s){ return __uint_as_float(((uint32_t)(uint16_t)s) << 16); }

// ---------------- embedding + max_norm -> bf16 features; also zero deg ----------------
__global__ __launch_bounds__(256) void k_embed(const int* __restrict__ x,
                                               const float* __restrict__ emb,
                                               uint32_t* __restrict__ hout,
                                               int* __restrict__ deg){
    int idx = blockIdx.x * 256 + threadIdx.x;
    if (idx < NN) deg[idx] = 0;
    int w = threadIdx.x >> 6, l = threadIdx.x & 63;
    int n = blockIdx.x * 4 + w;                       // N divisible by 4
    int r = x[n];
    const float2* e2 = (const float2*)emb;
    float2 v = e2[(size_t)r * 64 + l];
    float ss = v.x * v.x + v.y * v.y;
    #pragma unroll
    for (int off = 32; off; off >>= 1) ss += __shfl_xor(ss, off, 64);
    float sc = fminf(1.f, 1.f / (sqrtf(ss) + 1e-7f));
    hout[(size_t)n * 64 + l] = f2bf(v.x * sc) | (f2bf(v.y * sc) << 16);
}

// ---------------- weight pre-pack into MFMA B-fragment order ----------------
// wf[m][j0][ks][lane][i] bf16, m in {w1rel,w1root,w2rel,w2root}
// lane: col j = j0*16 + (lane&15), k = ks*32 + (lane>>4)*8 + i
__global__ __launch_bounds__(256) void k_pack(const float* __restrict__ w1rel, const float* __restrict__ w1root,
                                              const float* __restrict__ w2rel, const float* __restrict__ w2root,
                                              short* __restrict__ wf){
    int id = blockIdx.x * 256 + threadIdx.x;          // 65536 total
    int i = id & 7, lane = (id >> 3) & 63, ks = (id >> 9) & 3, j0 = (id >> 11) & 7, m = id >> 14;
    const float* W = (m == 0) ? w1rel : (m == 1) ? w1root : (m == 2) ? w2rel : w2root;
    int j = j0 * 16 + (lane & 15);
    int k = ks * 32 + (lane >> 4) * 8 + i;
    wf[id] = (short)f2bf(W[j * 128 + k]);
}

// ---------------- CSR build ----------------
__global__ __launch_bounds__(256) void k_count(const int* __restrict__ dst, int* __restrict__ deg, int E){
    int e = blockIdx.x * 256 + threadIdx.x;
    if (e < E) atomicAdd(&deg[dst[e]], 1);
}

__global__ __launch_bounds__(256) void k_scan_blocks(const int* __restrict__ deg, int* __restrict__ bsum, int N){
    __shared__ int red[256];
    int t = threadIdx.x;
    int base = blockIdx.x * 1024 + t * 4;
    int s = 0;
    #pragma unroll
    for (int i = 0; i < 4; ++i){ int idx = base + i; if (idx < N) s += deg[idx]; }
    red[t] = s; __syncthreads();
    for (int off = 128; off > 0; off >>= 1){
        if (t < off) red[t] += red[t + off];
        __syncthreads();
    }
    if (t == 0) bsum[blockIdx.x] = red[0];
}

__global__ void k_scan_top(const int* __restrict__ bsum, int* __restrict__ boff,
                           int* __restrict__ ptr, int nblocks, int N, int E){
    int l = threadIdx.x;                               // 64 threads
    int v0 = (l < nblocks) ? bsum[l] : 0;
    int i1 = 64 + l;
    int v1 = (i1 < nblocks) ? bsum[i1] : 0;
    int s0 = v0;
    #pragma unroll
    for (int off = 1; off < 64; off <<= 1){ int u = __shfl_up(s0, off, 64); if (l >= off) s0 += u; }
    int tot0 = __shfl(s0, 63, 64);
    int s1 = v1;
    #pragma unroll
    for (int off = 1; off < 64; off <<= 1){ int u = __shfl_up(s1, off, 64); if (l >= off) s1 += u; }
    s1 += tot0;
    if (l  < nblocks) boff[l]  = s0 - v0;
    if (i1 < nblocks) boff[i1] = s1 - v1;
    if (l == 0) ptr[N] = E;
}

__global__ __launch_bounds__(256) void k_scan_write(const int* __restrict__ deg,
                                                    const int* __restrict__ boff,
                                                    int* __restrict__ ptr, int* __restrict__ fill, int N){
    __shared__ int lds[256];
    int t = threadIdx.x;
    int base = blockIdx.x * 1024 + t * 4;
    int d[4]; int s = 0;
    #pragma unroll
    for (int i = 0; i < 4; ++i){ d[i] = (base + i < N) ? deg[base + i] : 0; s += d[i]; }
    lds[t] = s; __syncthreads();
    for (int off = 1; off < 256; off <<= 1){
        int v = (t >= off) ? lds[t - off] : 0;
        __syncthreads();
        lds[t] += v;
        __syncthreads();
    }
    int acc = lds[t] - s + boff[blockIdx.x];
    #pragma unroll
    for (int i = 0; i < 4; ++i){
        if (base + i < N){ ptr[base + i] = acc; fill[base + i] = 0; }
        acc += d[i];
    }
}

// packed edge record: (src_index, weight_bits)
__global__ __launch_bounds__(256) void k_fill(const int* __restrict__ src, const int* __restrict__ dst,
                                              const float* __restrict__ ew,
                                              const int* __restrict__ ptr, int* __restrict__ fill,
                                              uint2* __restrict__ cse, int E){
    int e = blockIdx.x * 256 + threadIdx.x;
    if (e < E){
        int d = dst[e];
        int pos = ptr[d] + atomicAdd(&fill[d], 1);
        cse[pos] = make_uint2((uint32_t)src[e], __float_as_uint(ew[e]));
    }
}

// ---------------- graph boundaries (batch is sorted) ----------------
__global__ __launch_bounds__(256) void k_gstart(const int* __restrict__ batch, int* __restrict__ gstart, int N){
    int i = blockIdx.x * 256 + threadIdx.x;
    if (i > N) return;
    int bprev = (i == 0) ? -1 : batch[i - 1];
    int bcur  = (i == N) ? NG : batch[i];
    for (int g = bprev + 1; g <= bcur; ++g) gstart[g] = i;
}

// ---------------- gather-aggregate only (bf16 rows, fp32 accum, bf16 out) ----------------
// 1 wave per node, no LDS, low VGPR -> high occupancy, 4-deep MLP
__global__ __launch_bounds__(256) void k_agg(const uint32_t* __restrict__ hin,
                                             uint32_t* __restrict__ aggo,
                                             const int* __restrict__ ptr,
                                             const uint2* __restrict__ cse){
    int w = threadIdx.x >> 6, l = threadIdx.x & 63;
    int n = blockIdx.x * 4 + w;
    int p0 = ptr[n], p1 = ptr[n + 1];
    float ax0 = 0, ay0 = 0, ax1 = 0, ay1 = 0, ax2 = 0, ay2 = 0, ax3 = 0, ay3 = 0;
    int e = p0;
    for (; e + 4 <= p1; e += 4){
        uint2 r0 = cse[e], r1 = cse[e + 1], r2 = cse[e + 2], r3 = cse[e + 3];
        uint32_t v0 = hin[(size_t)r0.x * 64 + l];
        uint32_t v1 = hin[(size_t)r1.x * 64 + l];
        uint32_t v2 = hin[(size_t)r2.x * 64 + l];
        uint32_t v3 = hin[(size_t)r3.x * 64 + l];
        float w0 = __uint_as_float(r0.y), w1 = __uint_as_float(r1.y);
        float w2 = __uint_as_float(r2.y), w3 = __uint_as_float(r3.y);
        ax0 += w0 * bflo(v0); ay0 += w0 * bfhi(v0);
        ax1 += w1 * bflo(v1); ay1 += w1 * bfhi(v1);
        ax2 += w2 * bflo(v2); ay2 += w2 * bfhi(v2);
        ax3 += w3 * bflo(v3); ay3 += w3 * bfhi(v3);
    }
    for (; e < p1; ++e){
        uint2 r0 = cse[e];
        uint32_t v0 = hin[(size_t)r0.x * 64 + l];
        float w0 = __uint_as_float(r0.y);
        ax0 += w0 * bflo(v0); ay0 += w0 * bfhi(v0);
    }
    float ax = (ax0 + ax1) + (ax2 + ax3);
    float ay = (ay0 + ay1) + (ay2 + ay3);
    aggo[(size_t)n * 64 + l] = f2bf(ax) | (f2bf(ay) << 16);
}

// ---------------- MFMA GEMM: out = relu(bias + agg@Wrel^T + h@Wroot^T) ----------------
// block = 256 (4 waves), 32 rows/wave (two 16-row tiles), 128 rows/block
__global__ __launch_bounds__(256) void k_gemm(const short* __restrict__ hin,
                                              const short* __restrict__ agg,
                                              short* __restrict__ hout,
                                              const bf16x8* __restrict__ wrel,   // [8][4][64]
                                              const bf16x8* __restrict__ wroot,
                                              const float* __restrict__ bias){
    int t = threadIdx.x, w = t >> 6, l = t & 63;
    int rbase = blockIdx.x * 128 + w * 32;
    int r0 = rbase + (l & 15);
    int rA0 = min(r0, NN - 1);
    int rA1 = min(r0 + 16, NN - 1);
    int kb = (l >> 4) * 8;

    bf16x8 aA[2][4], aH[2][4];
    const short* pa0 = agg + (size_t)rA0 * 128 + kb;
    const short* pa1 = agg + (size_t)rA1 * 128 + kb;
    const short* ph0 = hin + (size_t)rA0 * 128 + kb;
    const short* ph1 = hin + (size_t)rA1 * 128 + kb;
    #pragma unroll
    for (int ks = 0; ks < 4; ++ks){
        aA[0][ks] = *(const bf16x8*)(pa0 + ks * 32);
        aA[1][ks] = *(const bf16x8*)(pa1 + ks * 32);
        aH[0][ks] = *(const bf16x8*)(ph0 + ks * 32);
        aH[1][ks] = *(const bf16x8*)(ph1 + ks * 32);
    }

    for (int j0 = 0; j0 < 8; ++j0){
        f32x4 acc0 = {0.f, 0.f, 0.f, 0.f}, acc1 = {0.f, 0.f, 0.f, 0.f};
        #pragma unroll
        for (int ks = 0; ks < 4; ++ks){
            bf16x8 br = wrel [(j0 * 4 + ks) * 64 + l];
            bf16x8 bo = wroot[(j0 * 4 + ks) * 64 + l];
            acc0 = __builtin_amdgcn_mfma_f32_16x16x32_bf16(aA[0][ks], br, acc0, 0, 0, 0);
            acc0 = __builtin_amdgcn_mfma_f32_16x16x32_bf16(aH[0][ks], bo, acc0, 0, 0, 0);
            acc1 = __builtin_amdgcn_mfma_f32_16x16x32_bf16(aA[1][ks], br, acc1, 0, 0, 0);
            acc1 = __builtin_amdgcn_mfma_f32_16x16x32_bf16(aH[1][ks], bo, acc1, 0, 0, 0);
        }
        int col = j0 * 16 + (l & 15);
        float bv = bias[col];
        int rb = rbase + (l >> 4) * 4;
        #pragma unroll
        for (int r = 0; r < 4; ++r){
            int row = rb + r;
            if (row < NN){
                float v = fmaxf(acc0[r] + bv, 0.f);
                hout[(size_t)row * 128 + col] = (short)f2bf(v);
            }
            int row1 = rb + 16 + r;
            if (row1 < NN){
                float v = fmaxf(acc1[r] + bv, 0.f);
                hout[(size_t)row1 * 128 + col] = (short)f2bf(v);
            }
        }
    }
}

// ---------------- mean pool per graph (bf16 in, fp32 out) ----------------
__global__ __launch_bounds__(128) void k_pool(const short* __restrict__ h,
                                              const int* __restrict__ gstart,
                                              float* __restrict__ pooled){
    int g = blockIdx.x, f = threadIdx.x;               // 128 threads
    int s = gstart[g], e = gstart[g + 1];
    float a0 = 0, a1 = 0, a2 = 0, a3 = 0;
    int i = s;
    for (; i + 3 < e; i += 4){
        a0 += bf1(h[(size_t)i * 128 + f]);
        a1 += bf1(h[(size_t)(i + 1) * 128 + f]);
        a2 += bf1(h[(size_t)(i + 2) * 128 + f]);
        a3 += bf1(h[(size_t)(i + 3) * 128 + f]);
    }
    for (; i < e; ++i) a0 += bf1(h[(size_t)i * 128 + f]);
    float sum = (a0 + a1) + (a2 + a3);
    int cnt = e - s;
    pooled[g * 128 + f] = sum / fmaxf((float)cnt, 1.f);
}

// ---------------- classifier + softmax ----------------
__global__ __launch_bounds__(64) void k_cls(const float* __restrict__ pooled,
                                            const float* __restrict__ c1w, const float* __restrict__ c1b,
                                            const float* __restrict__ c2w, const float* __restrict__ c2b,
                                            float* __restrict__ out){
    __shared__ float pl[128];
    __shared__ float z[64];
    __shared__ float logits[2];
    int g = blockIdx.x, t = threadIdx.x;
    pl[t] = pooled[g * 128 + t];
    pl[t + 64] = pooled[g * 128 + 64 + t];
    __syncthreads();
    float acc = c1b[t];
    #pragma unroll 4
    for (int k = 0; k < 128; ++k) acc += pl[k] * c1w[t * 128 + k];
    z[t] = fmaxf(acc, 0.f);
    __syncthreads();
    if (t < 2){
        float a = c2b[t];
        for (int k = 0; k < 64; ++k) a += z[k] * c2w[t * 64 + k];
        logits[t] = a;
    }
    __syncthreads();
    if (t == 0){
        float m = fmaxf(logits[0], logits[1]);
        float e0 = expf(logits[0] - m), e1 = expf(logits[1] - m);
        float s = e0 + e1;
        out[g * 2 + 0] = e0 / s;
        out[g * 2 + 1] = e1 / s;
    }
}

extern "C" void kernel_launch(void* const* d_in, const int* in_sizes, int n_in,
                              void* d_out, int out_size, void* d_ws, size_t ws_size,
                              hipStream_t stream) {
    const int*   x      = (const int*)  d_in[0];
    const int*   eidx   = (const int*)  d_in[1];
    const float* ew     = (const float*)d_in[2];
    const int*   batch  = (const int*)  d_in[3];
    const float* emb    = (const float*)d_in[4];
    const float* w1rel  = (const float*)d_in[5];
    const float* b1     = (const float*)d_in[6];
    const float* w1root = (const float*)d_in[7];
    const float* w2rel  = (const float*)d_in[8];
    const float* b2     = (const float*)d_in[9];
    const float* w2root = (const float*)d_in[10];
    const float* c1w    = (const float*)d_in[11];
    const float* c1b    = (const float*)d_in[12];
    const float* c2w    = (const float*)d_in[13];
    const float* c2b    = (const float*)d_in[14];
    float* out = (float*)d_out;

    const int N = NN;                 // 100000
    const int E = NE;                 // 1600000

    char* p = (char*)d_ws;
    auto alloc = [&](size_t bytes) -> void* {
        void* r = (void*)p;
        p += (bytes + 255) & ~(size_t)255;
        return r;
    };
    uint32_t* hA   = (uint32_t*)alloc((size_t)N * 64 * 4);   // bf16x2 features
    uint32_t* hB   = (uint32_t*)alloc((size_t)N * 64 * 4);
    uint32_t* agg  = (uint32_t*)alloc((size_t)N * 64 * 4);
    int*   deg    = (int*)  alloc((size_t)N * 4);
    int*   fill   = (int*)  alloc((size_t)N * 4);
    int*   ptrA   = (int*)  alloc((size_t)(N + 1) * 4);
    int*   bsum   = (int*)  alloc(128 * 4);
    int*   boff   = (int*)  alloc(128 * 4);
    uint2* cse    = (uint2*)alloc((size_t)E * 8);
    int*   gstart = (int*)  alloc((NG + 1) * 4);
    float* pooled = (float*)alloc((size_t)NG * 128 * 4);
    short* wf     = (short*)alloc(4 * 16384 * 2);
    (void)alloc(65536);               // safety pad for clamped OOB reads

    const bf16x8* wf1rel  = (const bf16x8*)(wf);
    const bf16x8* wf1root = (const bf16x8*)(wf + 16384);
    const bf16x8* wf2rel  = (const bf16x8*)(wf + 32768);
    const bf16x8* wf2root = (const bf16x8*)(wf + 49152);

    k_embed<<<N / 4, 256, 0, stream>>>(x, emb, hA, deg);
    k_pack <<<256, 256, 0, stream>>>(w1rel, w1root, w2rel, w2root, wf);

    const int* esrc = eidx;
    const int* edst = eidx + E;
    k_count<<<(E + 255) / 256, 256, 0, stream>>>(edst, deg, E);
    int nsb = (N + 1023) / 1024;      // 98
    k_scan_blocks<<<nsb, 256, 0, stream>>>(deg, bsum, N);
    k_scan_top<<<1, 64, 0, stream>>>(bsum, boff, ptrA, nsb, N, E);
    k_scan_write<<<nsb, 256, 0, stream>>>(deg, boff, ptrA, fill, N);
    k_fill<<<(E + 255) / 256, 256, 0, stream>>>(esrc, edst, ew, ptrA, fill, cse, E);
    k_gstart<<<(N + 1 + 255) / 256, 256, 0, stream>>>(batch, gstart, N);

    int ngemm = (N + 127) / 128;      // 782
    k_agg <<<N / 4, 256, 0, stream>>>(hA, agg, ptrA, cse);
    k_gemm<<<ngemm, 256, 0, stream>>>((const short*)hA, (const short*)agg, (short*)hB,
                                      wf1rel, wf1root, b1);
    k_agg <<<N / 4, 256, 0, stream>>>(hB, agg, ptrA, cse);
    k_gemm<<<ngemm, 256, 0, stream>>>((const short*)hB, (const short*)agg, (short*)hA,
                                      wf2rel, wf2root, b2);

    k_pool<<<NG, 128, 0, stream>>>((const short*)hA, gstart, pooled);
    k_cls<<<NG, 64, 0, stream>>>(pooled, c1w, c1b, c2w, c2b, out);
}

// Round 4
// 404.974 us; speedup vs baseline: 3.0917x; 1.2388x over previous
//
#include <hip/hip_runtime.h>
#include <stdint.h>

// Sizes (fixed by problem)
#define NN 100000
#define NE 1600000
#define NG 256
#define NB 196          // buckets of 512 nodes: ceil(100000/512)
#define CHUNK 4096
#define NCH 391         // ceil(NE/CHUNK)

typedef __attribute__((ext_vector_type(8))) short bf16x8;   // 8 bf16 = 4 VGPR
typedef __attribute__((ext_vector_type(4))) float f32x4;

__device__ inline uint32_t f2bf(float f){
    uint32_t u = __float_as_uint(f);
    return (u + 0x7FFFu + ((u >> 16) & 1u)) >> 16;   // RNE bf16
}
__device__ inline float bflo(uint32_t u){ return __uint_as_float(u << 16); }
__device__ inline float bfhi(uint32_t u){ return __uint_as_float(u & 0xFFFF0000u); }
__device__ inline float bf1(short s){ return __uint_as_float(((uint32_t)(uint16_t)s) << 16); }

// ---------------- embedding + max_norm -> bf16 features; also zero bucket counts ----------------
__global__ __launch_bounds__(256) void k_embed(const int* __restrict__ x,
                                               const float* __restrict__ emb,
                                               uint32_t* __restrict__ hout,
                                               int* __restrict__ bcnt){
    int idx = blockIdx.x * 256 + threadIdx.x;
    if (idx < NB) bcnt[idx] = 0;
    int w = threadIdx.x >> 6, l = threadIdx.x & 63;
    int n = blockIdx.x * 4 + w;                       // N divisible by 4
    int r = x[n];
    const float2* e2 = (const float2*)emb;
    float2 v = e2[(size_t)r * 64 + l];
    float ss = v.x * v.x + v.y * v.y;
    #pragma unroll
    for (int off = 32; off; off >>= 1) ss += __shfl_xor(ss, off, 64);
    float sc = fminf(1.f, 1.f / (sqrtf(ss) + 1e-7f));
    hout[(size_t)n * 64 + l] = f2bf(v.x * sc) | (f2bf(v.y * sc) << 16);
}

// ---------------- weight pre-pack into MFMA B-fragment order ----------------
// wf[m][j0][ks][lane][i] bf16, m in {w1rel,w1root,w2rel,w2root}
// lane: col j = j0*16 + (lane&15), k = ks*32 + (lane>>4)*8 + i
__global__ __launch_bounds__(256) void k_pack(const float* __restrict__ w1rel, const float* __restrict__ w1root,
                                              const float* __restrict__ w2rel, const float* __restrict__ w2root,
                                              short* __restrict__ wf){
    int id = blockIdx.x * 256 + threadIdx.x;          // 65536 total
    int i = id & 7, lane = (id >> 3) & 63, ks = (id >> 9) & 3, j0 = (id >> 11) & 7, m = id >> 14;
    const float* W = (m == 0) ? w1rel : (m == 1) ? w1root : (m == 2) ? w2rel : w2root;
    int j = j0 * 16 + (lane & 15);
    int k = ks * 32 + (lane >> 4) * 8 + i;
    wf[id] = (short)f2bf(W[j * 128 + k]);
}

// ---------------- bucketed CSR build ----------------
// Phase 1: coarse histogram (bucket = dst >> 9)
__global__ __launch_bounds__(256) void k_bhist(const int* __restrict__ edst, int* __restrict__ bcnt){
    __shared__ int lh[NB];
    int t = threadIdx.x;
    int c0 = blockIdx.x * CHUNK;
    int cnt = min(CHUNK, NE - c0);
    if (t < NB) lh[t] = 0;
    __syncthreads();
    for (int i = t; i < cnt; i += 256) atomicAdd(&lh[edst[c0 + i] >> 9], 1);
    __syncthreads();
    if (t < NB && lh[t]) atomicAdd(&bcnt[t], lh[t]);
}

// Phase 2: scan bucket counts -> bbase[NB+1]; zero bfill; ptrA[NN] = NE
__global__ __launch_bounds__(256) void k_bscan(const int* __restrict__ bcnt,
                                               int* __restrict__ bbase, int* __restrict__ bfill,
                                               int* __restrict__ ptrA){
    __shared__ int sc[256];
    int t = threadIdx.x;
    int v = (t < NB) ? bcnt[t] : 0;
    sc[t] = v; __syncthreads();
    for (int off = 1; off < 256; off <<= 1){
        int u = (t >= off) ? sc[t - off] : 0;
        __syncthreads();
        sc[t] += u;
        __syncthreads();
    }
    if (t < NB){ bbase[t] = sc[t] - v; bfill[t] = 0; }
    if (t == 0){ bbase[NB] = NE; ptrA[NN] = NE; }
}

// Phase 3: chunk-local counting sort by bucket, contiguous global chunk writes
// record: x = src | (dst&511)<<23 , y = weight bits
__global__ __launch_bounds__(256) void k_bscatter(const int* __restrict__ esrc, const int* __restrict__ edst,
                                                  const float* __restrict__ ew,
                                                  const int* __restrict__ bbase, int* __restrict__ bfill,
                                                  uint2* __restrict__ cse2){
    __shared__ uint2 rec[CHUNK];
    __shared__ unsigned char slotb[CHUNK];
    __shared__ int hist[NB], start[NB], gbase[NB], sc[256];
    int t = threadIdx.x;
    int c0 = blockIdx.x * CHUNK;
    int cnt = min(CHUNK, NE - c0);
    if (t < NB) hist[t] = 0;
    __syncthreads();
    for (int i = t; i < cnt; i += 256) atomicAdd(&hist[edst[c0 + i] >> 9], 1);
    __syncthreads();
    int v = (t < NB) ? hist[t] : 0;
    sc[t] = v; __syncthreads();
    for (int off = 1; off < 256; off <<= 1){
        int u = (t >= off) ? sc[t - off] : 0;
        __syncthreads();
        sc[t] += u;
        __syncthreads();
    }
    if (t < NB){
        start[t] = sc[t] - v;
        if (v > 0) gbase[t] = bbase[t] + atomicAdd(&bfill[t], v);
    }
    __syncthreads();
    if (t < NB) hist[t] = 0;            // reuse as fill
    __syncthreads();
    for (int i = t; i < cnt; i += 256){
        int d = edst[c0 + i];
        int b = d >> 9;
        int slot = start[b] + atomicAdd(&hist[b], 1);
        rec[slot] = make_uint2((uint32_t)esrc[c0 + i] | ((uint32_t)(d & 511) << 23),
                               __float_as_uint(ew[c0 + i]));
        slotb[slot] = (unsigned char)b;
    }
    __syncthreads();
    for (int i = t; i < cnt; i += 256){
        int b = slotb[i];
        cse2[gbase[b] + (i - start[b])] = rec[i];
    }
}

// Phase 4: per-bucket fine CSR (512 nodes, ~8K edges); writes ptrA and final cse (clean src)
__global__ __launch_bounds__(256) void k_bcsr(const uint2* __restrict__ cse2,
                                              const int* __restrict__ bbase,
                                              int* __restrict__ ptrA,
                                              uint2* __restrict__ cse){
    __shared__ int cnt[512], sc[512], st[512];
    int t = threadIdx.x;
    int b = blockIdx.x;
    int ebase = bbase[b], eend = bbase[b + 1];
    int nb = b << 9;
    cnt[t] = 0; cnt[t + 256] = 0;
    __syncthreads();
    for (int i = ebase + t; i < eend; i += 256){
        uint2 r = cse2[i];
        atomicAdd(&cnt[r.x >> 23], 1);
    }
    __syncthreads();
    sc[t] = cnt[t]; sc[t + 256] = cnt[t + 256];
    __syncthreads();
    for (int off = 1; off < 512; off <<= 1){
        int v0 = (t >= off) ? sc[t - off] : 0;
        int v1 = sc[t + 256 - off];               // t+256 >= 256 >= off always
        __syncthreads();
        sc[t] += v0; sc[t + 256] += v1;
        __syncthreads();
    }
    st[t] = sc[t] - cnt[t];
    st[t + 256] = sc[t + 256] - cnt[t + 256];
    if (nb + t < NN)       ptrA[nb + t]       = ebase + st[t];
    if (nb + 256 + t < NN) ptrA[nb + 256 + t] = ebase + st[t + 256];
    cnt[t] = 0; cnt[t + 256] = 0;                 // reuse as fill
    __syncthreads();
    for (int i = ebase + t; i < eend; i += 256){
        uint2 r = cse2[i];
        int dr = r.x >> 23;
        int pos = st[dr] + atomicAdd(&cnt[dr], 1);
        cse[ebase + pos] = make_uint2(r.x & 0x7FFFFFu, r.y);
    }
}

// ---------------- graph boundaries (batch is sorted) ----------------
__global__ __launch_bounds__(256) void k_gstart(const int* __restrict__ batch, int* __restrict__ gstart, int N){
    int i = blockIdx.x * 256 + threadIdx.x;
    if (i > N) return;
    int bprev = (i == 0) ? -1 : batch[i - 1];
    int bcur  = (i == N) ? NG : batch[i];
    for (int g = bprev + 1; g <= bcur; ++g) gstart[g] = i;
}

// ---------------- gather-aggregate only (bf16 rows, fp32 accum, bf16 out) ----------------
__global__ __launch_bounds__(256) void k_agg(const uint32_t* __restrict__ hin,
                                             uint32_t* __restrict__ aggo,
                                             const int* __restrict__ ptr,
                                             const uint2* __restrict__ cse){
    int w = threadIdx.x >> 6, l = threadIdx.x & 63;
    int n = blockIdx.x * 4 + w;
    int p0 = ptr[n], p1 = ptr[n + 1];
    float ax0 = 0, ay0 = 0, ax1 = 0, ay1 = 0, ax2 = 0, ay2 = 0, ax3 = 0, ay3 = 0;
    int e = p0;
    for (; e + 4 <= p1; e += 4){
        uint2 r0 = cse[e], r1 = cse[e + 1], r2 = cse[e + 2], r3 = cse[e + 3];
        uint32_t v0 = hin[(size_t)r0.x * 64 + l];
        uint32_t v1 = hin[(size_t)r1.x * 64 + l];
        uint32_t v2 = hin[(size_t)r2.x * 64 + l];
        uint32_t v3 = hin[(size_t)r3.x * 64 + l];
        float w0 = __uint_as_float(r0.y), w1 = __uint_as_float(r1.y);
        float w2 = __uint_as_float(r2.y), w3 = __uint_as_float(r3.y);
        ax0 += w0 * bflo(v0); ay0 += w0 * bfhi(v0);
        ax1 += w1 * bflo(v1); ay1 += w1 * bfhi(v1);
        ax2 += w2 * bflo(v2); ay2 += w2 * bfhi(v2);
        ax3 += w3 * bflo(v3); ay3 += w3 * bfhi(v3);
    }
    for (; e < p1; ++e){
        uint2 r0 = cse[e];
        uint32_t v0 = hin[(size_t)r0.x * 64 + l];
        float w0 = __uint_as_float(r0.y);
        ax0 += w0 * bflo(v0); ay0 += w0 * bfhi(v0);
    }
    float ax = (ax0 + ax1) + (ax2 + ax3);
    float ay = (ay0 + ay1) + (ay2 + ay3);
    aggo[(size_t)n * 64 + l] = f2bf(ax) | (f2bf(ay) << 16);
}

// ---------------- MFMA GEMM: out = relu(bias + agg@Wrel^T + h@Wroot^T) ----------------
__global__ __launch_bounds__(256) void k_gemm(const short* __restrict__ hin,
                                              const short* __restrict__ agg,
                                              short* __restrict__ hout,
                                              const bf16x8* __restrict__ wrel,   // [8][4][64]
                                              const bf16x8* __restrict__ wroot,
                                              const float* __restrict__ bias){
    int t = threadIdx.x, w = t >> 6, l = t & 63;
    int rbase = blockIdx.x * 128 + w * 32;
    int r0 = rbase + (l & 15);
    int rA0 = min(r0, NN - 1);
    int rA1 = min(r0 + 16, NN - 1);
    int kb = (l >> 4) * 8;

    bf16x8 aA[2][4], aH[2][4];
    const short* pa0 = agg + (size_t)rA0 * 128 + kb;
    const short* pa1 = agg + (size_t)rA1 * 128 + kb;
    const short* ph0 = hin + (size_t)rA0 * 128 + kb;
    const short* ph1 = hin + (size_t)rA1 * 128 + kb;
    #pragma unroll
    for (int ks = 0; ks < 4; ++ks){
        aA[0][ks] = *(const bf16x8*)(pa0 + ks * 32);
        aA[1][ks] = *(const bf16x8*)(pa1 + ks * 32);
        aH[0][ks] = *(const bf16x8*)(ph0 + ks * 32);
        aH[1][ks] = *(const bf16x8*)(ph1 + ks * 32);
    }

    for (int j0 = 0; j0 < 8; ++j0){
        f32x4 acc0 = {0.f, 0.f, 0.f, 0.f}, acc1 = {0.f, 0.f, 0.f, 0.f};
        #pragma unroll
        for (int ks = 0; ks < 4; ++ks){
            bf16x8 br = wrel [(j0 * 4 + ks) * 64 + l];
            bf16x8 bo = wroot[(j0 * 4 + ks) * 64 + l];
            acc0 = __builtin_amdgcn_mfma_f32_16x16x32_bf16(aA[0][ks], br, acc0, 0, 0, 0);
            acc0 = __builtin_amdgcn_mfma_f32_16x16x32_bf16(aH[0][ks], bo, acc0, 0, 0, 0);
            acc1 = __builtin_amdgcn_mfma_f32_16x16x32_bf16(aA[1][ks], br, acc1, 0, 0, 0);
            acc1 = __builtin_amdgcn_mfma_f32_16x16x32_bf16(aH[1][ks], bo, acc1, 0, 0, 0);
        }
        int col = j0 * 16 + (l & 15);
        float bv = bias[col];
        int rb = rbase + (l >> 4) * 4;
        #pragma unroll
        for (int r = 0; r < 4; ++r){
            int row = rb + r;
            if (row < NN){
                float v = fmaxf(acc0[r] + bv, 0.f);
                hout[(size_t)row * 128 + col] = (short)f2bf(v);
            }
            int row1 = rb + 16 + r;
            if (row1 < NN){
                float v = fmaxf(acc1[r] + bv, 0.f);
                hout[(size_t)row1 * 128 + col] = (short)f2bf(v);
            }
        }
    }
}

// ---------------- mean pool per graph (bf16 in, fp32 out) ----------------
__global__ __launch_bounds__(128) void k_pool(const short* __restrict__ h,
                                              const int* __restrict__ gstart,
                                              float* __restrict__ pooled){
    int g = blockIdx.x, f = threadIdx.x;               // 128 threads
    int s = gstart[g], e = gstart[g + 1];
    float a0 = 0, a1 = 0, a2 = 0, a3 = 0;
    int i = s;
    for (; i + 3 < e; i += 4){
        a0 += bf1(h[(size_t)i * 128 + f]);
        a1 += bf1(h[(size_t)(i + 1) * 128 + f]);
        a2 += bf1(h[(size_t)(i + 2) * 128 + f]);
        a3 += bf1(h[(size_t)(i + 3) * 128 + f]);
    }
    for (; i < e; ++i) a0 += bf1(h[(size_t)i * 128 + f]);
    float sum = (a0 + a1) + (a2 + a3);
    int cnt = e - s;
    pooled[g * 128 + f] = sum / fmaxf((float)cnt, 1.f);
}

// ---------------- classifier + softmax ----------------
__global__ __launch_bounds__(64) void k_cls(const float* __restrict__ pooled,
                                            const float* __restrict__ c1w, const float* __restrict__ c1b,
                                            const float* __restrict__ c2w, const float* __restrict__ c2b,
                                            float* __restrict__ out){
    __shared__ float pl[128];
    __shared__ float z[64];
    __shared__ float logits[2];
    int g = blockIdx.x, t = threadIdx.x;
    pl[t] = pooled[g * 128 + t];
    pl[t + 64] = pooled[g * 128 + 64 + t];
    __syncthreads();
    float acc = c1b[t];
    #pragma unroll 4
    for (int k = 0; k < 128; ++k) acc += pl[k] * c1w[t * 128 + k];
    z[t] = fmaxf(acc, 0.f);
    __syncthreads();
    if (t < 2){
        float a = c2b[t];
        for (int k = 0; k < 64; ++k) a += z[k] * c2w[t * 64 + k];
        logits[t] = a;
    }
    __syncthreads();
    if (t == 0){
        float m = fmaxf(logits[0], logits[1]);
        float e0 = expf(logits[0] - m), e1 = expf(logits[1] - m);
        float s = e0 + e1;
        out[g * 2 + 0] = e0 / s;
        out[g * 2 + 1] = e1 / s;
    }
}

extern "C" void kernel_launch(void* const* d_in, const int* in_sizes, int n_in,
                              void* d_out, int out_size, void* d_ws, size_t ws_size,
                              hipStream_t stream) {
    const int*   x      = (const int*)  d_in[0];
    const int*   eidx   = (const int*)  d_in[1];
    const float* ew     = (const float*)d_in[2];
    const int*   batch  = (const int*)  d_in[3];
    const float* emb    = (const float*)d_in[4];
    const float* w1rel  = (const float*)d_in[5];
    const float* b1     = (const float*)d_in[6];
    const float* w1root = (const float*)d_in[7];
    const float* w2rel  = (const float*)d_in[8];
    const float* b2     = (const float*)d_in[9];
    const float* w2root = (const float*)d_in[10];
    const float* c1w    = (const float*)d_in[11];
    const float* c1b    = (const float*)d_in[12];
    const float* c2w    = (const float*)d_in[13];
    const float* c2b    = (const float*)d_in[14];
    float* out = (float*)d_out;

    const int N = NN;                 // 100000
    const int E = NE;                 // 1600000

    char* p = (char*)d_ws;
    auto alloc = [&](size_t bytes) -> void* {
        void* r = (void*)p;
        p += (bytes + 255) & ~(size_t)255;
        return r;
    };
    uint32_t* hA   = (uint32_t*)alloc((size_t)N * 64 * 4);   // bf16x2 features
    uint32_t* hB   = (uint32_t*)alloc((size_t)N * 64 * 4);
    uint32_t* agg  = (uint32_t*)alloc((size_t)N * 64 * 4);
    int*   ptrA   = (int*)  alloc((size_t)(N + 1) * 4);
    int*   bcnt   = (int*)  alloc(NB * 4);
    int*   bbase  = (int*)  alloc((NB + 1) * 4);
    int*   bfill  = (int*)  alloc(NB * 4);
    uint2* cse2   = (uint2*)alloc((size_t)E * 8);
    uint2* cse    = (uint2*)alloc((size_t)E * 8);
    int*   gstart = (int*)  alloc((NG + 1) * 4);
    float* pooled = (float*)alloc((size_t)NG * 128 * 4);
    short* wf     = (short*)alloc(4 * 16384 * 2);
    (void)alloc(65536);               // safety pad for clamped OOB reads

    const bf16x8* wf1rel  = (const bf16x8*)(wf);
    const bf16x8* wf1root = (const bf16x8*)(wf + 16384);
    const bf16x8* wf2rel  = (const bf16x8*)(wf + 32768);
    const bf16x8* wf2root = (const bf16x8*)(wf + 49152);

    const int* esrc = eidx;
    const int* edst = eidx + E;

    k_embed<<<N / 4, 256, 0, stream>>>(x, emb, hA, bcnt);
    k_pack <<<256, 256, 0, stream>>>(w1rel, w1root, w2rel, w2root, wf);

    k_bhist   <<<NCH, 256, 0, stream>>>(edst, bcnt);
    k_bscan   <<<1,   256, 0, stream>>>(bcnt, bbase, bfill, ptrA);
    k_bscatter<<<NCH, 256, 0, stream>>>(esrc, edst, ew, bbase, bfill, cse2);
    k_bcsr    <<<NB,  256, 0, stream>>>(cse2, bbase, ptrA, cse);
    k_gstart  <<<(N + 1 + 255) / 256, 256, 0, stream>>>(batch, gstart, N);

    int ngemm = (N + 127) / 128;      // 782
    k_agg <<<N / 4, 256, 0, stream>>>(hA, agg, ptrA, cse);
    k_gemm<<<ngemm, 256, 0, stream>>>((const short*)hA, (const short*)agg, (short*)hB,
                                      wf1rel, wf1root, b1);
    k_agg <<<N / 4, 256, 0, stream>>>(hB, agg, ptrA, cse);
    k_gemm<<<ngemm, 256, 0, stream>>>((const short*)hB, (const short*)agg, (short*)hA,
                                      wf2rel, wf2root, b2);

    k_pool<<<NG, 128, 0, stream>>>((const short*)hA, gstart, pooled);
    k_cls<<<NG, 64, 0, stream>>>(pooled, c1w, c1b, c2w, c2b, out);
}

// Round 5
// 376.998 us; speedup vs baseline: 3.3211x; 1.0742x over previous
//
#include <hip/hip_runtime.h>
#include <stdint.h>

// Sizes (fixed by problem)
#define NN 100000
#define NE 1600000
#define NG 256
#define NB 196          // buckets of 512 nodes: ceil(100000/512)
#define CHUNK 4096
#define NCH 391         // ceil(NE/CHUNK)
#define NGS 392         // gstart blocks: ceil((NN+1)/256)

typedef __attribute__((ext_vector_type(8))) short bf16x8;   // 8 bf16 = 4 VGPR
typedef __attribute__((ext_vector_type(4))) float f32x4;

__device__ inline uint32_t f2bf(float f){
    uint32_t u = __float_as_uint(f);
    return (u + 0x7FFFu + ((u >> 16) & 1u)) >> 16;   // RNE bf16
}
__device__ inline float bflo(uint32_t u){ return __uint_as_float(u << 16); }
__device__ inline float bfhi(uint32_t u){ return __uint_as_float(u & 0xFFFF0000u); }
__device__ inline float bf1(short s){ return __uint_as_float(((uint32_t)(uint16_t)s) << 16); }

// ---------------- weight pre-pack into MFMA B-fragment order; zero bcnt ----------------
// wf[m][j0][ks][lane][i] bf16, m in {w1rel,w1root,w2rel,w2root}
__global__ __launch_bounds__(256) void k_pack(const float* __restrict__ w1rel, const float* __restrict__ w1root,
                                              const float* __restrict__ w2rel, const float* __restrict__ w2root,
                                              short* __restrict__ wf, int* __restrict__ bcnt){
    int id = blockIdx.x * 256 + threadIdx.x;          // 65536 total
    if (id < NB) bcnt[id] = 0;
    int i = id & 7, lane = (id >> 3) & 63, ks = (id >> 9) & 3, j0 = (id >> 11) & 7, m = id >> 14;
    const float* W = (m == 0) ? w1rel : (m == 1) ? w1root : (m == 2) ? w2rel : w2root;
    int j = j0 * 16 + (lane & 15);
    int k = ks * 32 + (lane >> 4) * 8 + i;
    wf[id] = (short)f2bf(W[j * 128 + k]);
}

// ---------------- fused: embedding+max_norm | coarse hist | graph boundaries ----------------
__global__ __launch_bounds__(256) void k_embed(const int* __restrict__ x,
                                               const float* __restrict__ emb,
                                               uint32_t* __restrict__ hout,
                                               const int* __restrict__ edst,
                                               int* __restrict__ bcnt,
                                               const int* __restrict__ batch,
                                               int* __restrict__ gstart){
    int bid = blockIdx.x;
    if (bid < NN / 4){
        int w = threadIdx.x >> 6, l = threadIdx.x & 63;
        int n = bid * 4 + w;
        int r = x[n];
        const float2* e2 = (const float2*)emb;
        float2 v = e2[(size_t)r * 64 + l];
        float ss = v.x * v.x + v.y * v.y;
        #pragma unroll
        for (int off = 32; off; off >>= 1) ss += __shfl_xor(ss, off, 64);
        float sc = fminf(1.f, 1.f / (sqrtf(ss) + 1e-7f));
        hout[(size_t)n * 64 + l] = f2bf(v.x * sc) | (f2bf(v.y * sc) << 16);
    } else if (bid < NN / 4 + NCH){
        __shared__ int lh[NB];
        int t = threadIdx.x;
        int c0 = (bid - NN / 4) * CHUNK;
        int cnt = min(CHUNK, NE - c0);
        if (t < NB) lh[t] = 0;
        __syncthreads();
        for (int i = t; i < cnt; i += 256) atomicAdd(&lh[edst[c0 + i] >> 9], 1);
        __syncthreads();
        if (t < NB && lh[t]) atomicAdd(&bcnt[t], lh[t]);
    } else {
        int i = (bid - NN / 4 - NCH) * 256 + threadIdx.x;
        if (i > NN) return;
        int bprev = (i == 0) ? -1 : batch[i - 1];
        int bcur  = (i == NN) ? NG : batch[i];
        for (int g = bprev + 1; g <= bcur; ++g) gstart[g] = i;
    }
}

// ---------------- scan bucket counts -> bbase[NB+1]; zero bfill; ptrA[NN] = NE ----------------
__global__ __launch_bounds__(256) void k_bscan(const int* __restrict__ bcnt,
                                               int* __restrict__ bbase, int* __restrict__ bfill,
                                               int* __restrict__ ptrA){
    __shared__ int sc[256];
    int t = threadIdx.x;
    int v = (t < NB) ? bcnt[t] : 0;
    sc[t] = v; __syncthreads();
    for (int off = 1; off < 256; off <<= 1){
        int u = (t >= off) ? sc[t - off] : 0;
        __syncthreads();
        sc[t] += u;
        __syncthreads();
    }
    if (t < NB){ bbase[t] = sc[t] - v; bfill[t] = 0; }
    if (t == 0){ bbase[NB] = NE; ptrA[NN] = NE; }
}

// ---------------- chunk-local counting sort by bucket, contiguous global chunk writes ----------------
// record: x = src | (dst&511)<<23 , y = weight bits
__global__ __launch_bounds__(256) void k_bscatter(const int* __restrict__ esrc, const int* __restrict__ edst,
                                                  const float* __restrict__ ew,
                                                  const int* __restrict__ bbase, int* __restrict__ bfill,
                                                  uint2* __restrict__ cse2){
    __shared__ uint2 rec[CHUNK];
    __shared__ unsigned char slotb[CHUNK];
    __shared__ int hist[NB], start[NB], gbase[NB], sc[256];
    int t = threadIdx.x;
    int c0 = blockIdx.x * CHUNK;
    int cnt = min(CHUNK, NE - c0);
    if (t < NB) hist[t] = 0;
    __syncthreads();
    for (int i = t; i < cnt; i += 256) atomicAdd(&hist[edst[c0 + i] >> 9], 1);
    __syncthreads();
    int v = (t < NB) ? hist[t] : 0;
    sc[t] = v; __syncthreads();
    for (int off = 1; off < 256; off <<= 1){
        int u = (t >= off) ? sc[t - off] : 0;
        __syncthreads();
        sc[t] += u;
        __syncthreads();
    }
    if (t < NB){
        start[t] = sc[t] - v;
        if (v > 0) gbase[t] = bbase[t] + atomicAdd(&bfill[t], v);
    }
    __syncthreads();
    if (t < NB) hist[t] = 0;            // reuse as fill
    __syncthreads();
    for (int i = t; i < cnt; i += 256){
        int d = edst[c0 + i];
        int b = d >> 9;
        int slot = start[b] + atomicAdd(&hist[b], 1);
        rec[slot] = make_uint2((uint32_t)esrc[c0 + i] | ((uint32_t)(d & 511) << 23),
                               __float_as_uint(ew[c0 + i]));
        slotb[slot] = (unsigned char)b;
    }
    __syncthreads();
    for (int i = t; i < cnt; i += 256){
        int b = slotb[i];
        cse2[gbase[b] + (i - start[b])] = rec[i];
    }
}

// ---------------- per-bucket fine CSR (512 nodes); writes ptrA and final cse (clean src) ----------------
__global__ __launch_bounds__(256) void k_bcsr(const uint2* __restrict__ cse2,
                                              const int* __restrict__ bbase,
                                              int* __restrict__ ptrA,
                                              uint2* __restrict__ cse){
    __shared__ int cnt[512], sc[512], st[512];
    int t = threadIdx.x;
    int b = blockIdx.x;
    int ebase = bbase[b], eend = bbase[b + 1];
    int nb = b << 9;
    cnt[t] = 0; cnt[t + 256] = 0;
    __syncthreads();
    for (int i = ebase + t; i < eend; i += 256){
        uint2 r = cse2[i];
        atomicAdd(&cnt[r.x >> 23], 1);
    }
    __syncthreads();
    sc[t] = cnt[t]; sc[t + 256] = cnt[t + 256];
    __syncthreads();
    for (int off = 1; off < 512; off <<= 1){
        int v0 = (t >= off) ? sc[t - off] : 0;
        int v1 = sc[t + 256 - off];               // t+256 >= 256 >= off always
        __syncthreads();
        sc[t] += v0; sc[t + 256] += v1;
        __syncthreads();
    }
    st[t] = sc[t] - cnt[t];
    st[t + 256] = sc[t + 256] - cnt[t + 256];
    if (nb + t < NN)       ptrA[nb + t]       = ebase + st[t];
    if (nb + 256 + t < NN) ptrA[nb + 256 + t] = ebase + st[t + 256];
    cnt[t] = 0; cnt[t + 256] = 0;                 // reuse as fill
    __syncthreads();
    for (int i = ebase + t; i < eend; i += 256){
        uint2 r = cse2[i];
        int dr = r.x >> 23;
        int pos = st[dr] + atomicAdd(&cnt[dr], 1);
        cse[ebase + pos] = make_uint2(r.x & 0x7FFFFFu, r.y);
    }
}

// ---------------- gather-aggregate: 2 rows per VMEM instr (half-wave per edge) ----------------
// wave = node; halves h=0/1 take alternating edges; lane covers cols 4c..4c+3 (uint2)
__global__ __launch_bounds__(256) void k_agg(const uint32_t* __restrict__ hin,
                                             uint32_t* __restrict__ aggo,
                                             const int* __restrict__ ptr,
                                             const uint2* __restrict__ cse){
    int w = threadIdx.x >> 6, l = threadIdx.x & 63;
    int h = l >> 5, c = l & 31;
    int n = blockIdx.x * 4 + w;
    int p0 = ptr[n], p1 = ptr[n + 1];
    const uint2* hin2 = (const uint2*)hin;            // row = 32 x uint2
    float a0 = 0, a1 = 0, a2 = 0, a3 = 0;             // chain A
    float b0 = 0, b1 = 0, b2 = 0, b3 = 0;             // chain B
    int e = p0;
    for (; e + 8 <= p1; e += 8){                      // 8 edges: 4 row loads in flight
        uint2 rA0 = cse[e + 2 * h],     rB0 = cse[e + 2 * h + 1];
        uint2 rA1 = cse[e + 4 + 2 * h], rB1 = cse[e + 4 + 2 * h + 1];
        uint2 vA0 = hin2[(size_t)rA0.x * 32 + c];
        uint2 vB0 = hin2[(size_t)rB0.x * 32 + c];
        uint2 vA1 = hin2[(size_t)rA1.x * 32 + c];
        uint2 vB1 = hin2[(size_t)rB1.x * 32 + c];
        float wA0 = __uint_as_float(rA0.y), wB0 = __uint_as_float(rB0.y);
        float wA1 = __uint_as_float(rA1.y), wB1 = __uint_as_float(rB1.y);
        a0 += wA0 * bflo(vA0.x); a1 += wA0 * bfhi(vA0.x);
        a2 += wA0 * bflo(vA0.y); a3 += wA0 * bfhi(vA0.y);
        b0 += wB0 * bflo(vB0.x); b1 += wB0 * bfhi(vB0.x);
        b2 += wB0 * bflo(vB0.y); b3 += wB0 * bfhi(vB0.y);
        a0 += wA1 * bflo(vA1.x); a1 += wA1 * bfhi(vA1.x);
        a2 += wA1 * bflo(vA1.y); a3 += wA1 * bfhi(vA1.y);
        b0 += wB1 * bflo(vB1.x); b1 += wB1 * bfhi(vB1.x);
        b2 += wB1 * bflo(vB1.y); b3 += wB1 * bfhi(vB1.y);
    }
    for (; e + 4 <= p1; e += 4){                      // 4 edges
        uint2 rA = cse[e + 2 * h], rB = cse[e + 2 * h + 1];
        uint2 vA = hin2[(size_t)rA.x * 32 + c];
        uint2 vB = hin2[(size_t)rB.x * 32 + c];
        float wA = __uint_as_float(rA.y), wB = __uint_as_float(rB.y);
        a0 += wA * bflo(vA.x); a1 += wA * bfhi(vA.x);
        a2 += wA * bflo(vA.y); a3 += wA * bfhi(vA.y);
        b0 += wB * bflo(vB.x); b1 += wB * bfhi(vB.x);
        b2 += wB * bflo(vB.y); b3 += wB * bfhi(vB.y);
    }
    for (; e < p1; e += 2){                           // tail: up to 2 edges across halves
        int idx = e + h;
        bool act = idx < p1;
        uint2 r = act ? cse[idx] : make_uint2(0u, 0u);
        uint2 v = hin2[(size_t)r.x * 32 + c];
        float wt = act ? __uint_as_float(r.y) : 0.f;
        a0 += wt * bflo(v.x); a1 += wt * bfhi(v.x);
        a2 += wt * bflo(v.y); a3 += wt * bfhi(v.y);
    }
    a0 += b0; a1 += b1; a2 += b2; a3 += b3;
    a0 += __shfl_xor(a0, 32, 64);
    a1 += __shfl_xor(a1, 32, 64);
    a2 += __shfl_xor(a2, 32, 64);
    a3 += __shfl_xor(a3, 32, 64);
    if (h == 0){
        uint2 o;
        o.x = f2bf(a0) | (f2bf(a1) << 16);
        o.y = f2bf(a2) | (f2bf(a3) << 16);
        ((uint2*)aggo)[(size_t)n * 32 + c] = o;
    }
}

// ---------------- MFMA GEMM: out = relu(bias + agg@Wrel^T + h@Wroot^T) ----------------
__global__ __launch_bounds__(256) void k_gemm(const short* __restrict__ hin,
                                              const short* __restrict__ agg,
                                              short* __restrict__ hout,
                                              const bf16x8* __restrict__ wrel,   // [8][4][64]
                                              const bf16x8* __restrict__ wroot,
                                              const float* __restrict__ bias){
    int t = threadIdx.x, w = t >> 6, l = t & 63;
    int rbase = blockIdx.x * 128 + w * 32;
    int r0 = rbase + (l & 15);
    int rA0 = min(r0, NN - 1);
    int rA1 = min(r0 + 16, NN - 1);
    int kb = (l >> 4) * 8;

    bf16x8 aA[2][4], aH[2][4];
    const short* pa0 = agg + (size_t)rA0 * 128 + kb;
    const short* pa1 = agg + (size_t)rA1 * 128 + kb;
    const short* ph0 = hin + (size_t)rA0 * 128 + kb;
    const short* ph1 = hin + (size_t)rA1 * 128 + kb;
    #pragma unroll
    for (int ks = 0; ks < 4; ++ks){
        aA[0][ks] = *(const bf16x8*)(pa0 + ks * 32);
        aA[1][ks] = *(const bf16x8*)(pa1 + ks * 32);
        aH[0][ks] = *(const bf16x8*)(ph0 + ks * 32);
        aH[1][ks] = *(const bf16x8*)(ph1 + ks * 32);
    }

    for (int j0 = 0; j0 < 8; ++j0){
        f32x4 acc0 = {0.f, 0.f, 0.f, 0.f}, acc1 = {0.f, 0.f, 0.f, 0.f};
        #pragma unroll
        for (int ks = 0; ks < 4; ++ks){
            bf16x8 br = wrel [(j0 * 4 + ks) * 64 + l];
            bf16x8 bo = wroot[(j0 * 4 + ks) * 64 + l];
            acc0 = __builtin_amdgcn_mfma_f32_16x16x32_bf16(aA[0][ks], br, acc0, 0, 0, 0);
            acc0 = __builtin_amdgcn_mfma_f32_16x16x32_bf16(aH[0][ks], bo, acc0, 0, 0, 0);
            acc1 = __builtin_amdgcn_mfma_f32_16x16x32_bf16(aA[1][ks], br, acc1, 0, 0, 0);
            acc1 = __builtin_amdgcn_mfma_f32_16x16x32_bf16(aH[1][ks], bo, acc1, 0, 0, 0);
        }
        int col = j0 * 16 + (l & 15);
        float bv = bias[col];
        int rb = rbase + (l >> 4) * 4;
        #pragma unroll
        for (int r = 0; r < 4; ++r){
            int row = rb + r;
            if (row < NN){
                float v = fmaxf(acc0[r] + bv, 0.f);
                hout[(size_t)row * 128 + col] = (short)f2bf(v);
            }
            int row1 = rb + 16 + r;
            if (row1 < NN){
                float v = fmaxf(acc1[r] + bv, 0.f);
                hout[(size_t)row1 * 128 + col] = (short)f2bf(v);
            }
        }
    }
}

// ---------------- fused mean-pool + classifier + softmax ----------------
__global__ __launch_bounds__(128) void k_poolcls(const short* __restrict__ h,
                                                 const int* __restrict__ gstart,
                                                 const float* __restrict__ c1w, const float* __restrict__ c1b,
                                                 const float* __restrict__ c2w, const float* __restrict__ c2b,
                                                 float* __restrict__ out){
    __shared__ float pl[128];
    __shared__ float z[64];
    __shared__ float logits[2];
    int g = blockIdx.x, t = threadIdx.x;
    int s = gstart[g], e = gstart[g + 1];
    float a0 = 0, a1 = 0, a2 = 0, a3 = 0;
    int i = s;
    for (; i + 3 < e; i += 4){
        a0 += bf1(h[(size_t)i * 128 + t]);
        a1 += bf1(h[(size_t)(i + 1) * 128 + t]);
        a2 += bf1(h[(size_t)(i + 2) * 128 + t]);
        a3 += bf1(h[(size_t)(i + 3) * 128 + t]);
    }
    for (; i < e; ++i) a0 += bf1(h[(size_t)i * 128 + t]);
    float sum = (a0 + a1) + (a2 + a3);
    int cnt = e - s;
    pl[t] = sum / fmaxf((float)cnt, 1.f);
    __syncthreads();
    if (t < 64){
        float acc = c1b[t];
        #pragma unroll 4
        for (int k = 0; k < 128; ++k) acc += pl[k] * c1w[t * 128 + k];
        z[t] = fmaxf(acc, 0.f);
    }
    __syncthreads();
    if (t < 2){
        float a = c2b[t];
        for (int k = 0; k < 64; ++k) a += z[k] * c2w[t * 64 + k];
        logits[t] = a;
    }
    __syncthreads();
    if (t == 0){
        float m = fmaxf(logits[0], logits[1]);
        float e0 = expf(logits[0] - m), e1 = expf(logits[1] - m);
        float ss = e0 + e1;
        out[g * 2 + 0] = e0 / ss;
        out[g * 2 + 1] = e1 / ss;
    }
}

extern "C" void kernel_launch(void* const* d_in, const int* in_sizes, int n_in,
                              void* d_out, int out_size, void* d_ws, size_t ws_size,
                              hipStream_t stream) {
    const int*   x      = (const int*)  d_in[0];
    const int*   eidx   = (const int*)  d_in[1];
    const float* ew     = (const float*)d_in[2];
    const int*   batch  = (const int*)  d_in[3];
    const float* emb    = (const float*)d_in[4];
    const float* w1rel  = (const float*)d_in[5];
    const float* b1     = (const float*)d_in[6];
    const float* w1root = (const float*)d_in[7];
    const float* w2rel  = (const float*)d_in[8];
    const float* b2     = (const float*)d_in[9];
    const float* w2root = (const float*)d_in[10];
    const float* c1w    = (const float*)d_in[11];
    const float* c1b    = (const float*)d_in[12];
    const float* c2w    = (const float*)d_in[13];
    const float* c2b    = (const float*)d_in[14];
    float* out = (float*)d_out;

    const int N = NN;                 // 100000
    const int E = NE;                 // 1600000

    char* p = (char*)d_ws;
    auto alloc = [&](size_t bytes) -> void* {
        void* r = (void*)p;
        p += (bytes + 255) & ~(size_t)255;
        return r;
    };
    uint32_t* hA   = (uint32_t*)alloc((size_t)N * 64 * 4);   // bf16x2 features
    uint32_t* hB   = (uint32_t*)alloc((size_t)N * 64 * 4);
    uint32_t* agg  = (uint32_t*)alloc((size_t)N * 64 * 4);
    int*   ptrA   = (int*)  alloc((size_t)(N + 1) * 4);
    int*   bcnt   = (int*)  alloc(NB * 4);
    int*   bbase  = (int*)  alloc((NB + 1) * 4);
    int*   bfill  = (int*)  alloc(NB * 4);
    uint2* cse2   = (uint2*)alloc((size_t)E * 8);
    uint2* cse    = (uint2*)alloc((size_t)E * 8);
    int*   gstart = (int*)  alloc((NG + 1) * 4);
    short* wf     = (short*)alloc(4 * 16384 * 2);
    (void)alloc(65536);               // safety pad for clamped OOB reads

    const bf16x8* wf1rel  = (const bf16x8*)(wf);
    const bf16x8* wf1root = (const bf16x8*)(wf + 16384);
    const bf16x8* wf2rel  = (const bf16x8*)(wf + 32768);
    const bf16x8* wf2root = (const bf16x8*)(wf + 49152);

    const int* esrc = eidx;
    const int* edst = eidx + E;

    k_pack <<<256, 256, 0, stream>>>(w1rel, w1root, w2rel, w2root, wf, bcnt);
    k_embed<<<N / 4 + NCH + NGS, 256, 0, stream>>>(x, emb, hA, edst, bcnt, batch, gstart);

    k_bscan   <<<1,   256, 0, stream>>>(bcnt, bbase, bfill, ptrA);
    k_bscatter<<<NCH, 256, 0, stream>>>(esrc, edst, ew, bbase, bfill, cse2);
    k_bcsr    <<<NB,  256, 0, stream>>>(cse2, bbase, ptrA, cse);

    int ngemm = (N + 127) / 128;      // 782
    k_agg <<<N / 4, 256, 0, stream>>>(hA, agg, ptrA, cse);
    k_gemm<<<ngemm, 256, 0, stream>>>((const short*)hA, (const short*)agg, (short*)hB,
                                      wf1rel, wf1root, b1);
    k_agg <<<N / 4, 256, 0, stream>>>(hB, agg, ptrA, cse);
    k_gemm<<<ngemm, 256, 0, stream>>>((const short*)hB, (const short*)agg, (short*)hA,
                                      wf2rel, wf2root, b2);

    k_poolcls<<<NG, 128, 0, stream>>>((const short*)hA, gstart, c1w, c1b, c2w, c2b, out);
}

// Round 6
// 362.635 us; speedup vs baseline: 3.4526x; 1.0396x over previous
//
#include <hip/hip_runtime.h>
#include <stdint.h>

// Sizes (fixed by problem)
#define NN 100000
#define NE 1600000
#define NG 256
#define NB 391          // buckets of 256 nodes: ceil(100000/256)
#define CHUNK 4096
#define NCH 391         // ceil(NE/CHUNK)
#define NGS 392         // gstart blocks: ceil((NN+1)/256)

typedef __attribute__((ext_vector_type(8))) short bf16x8;   // 8 bf16 = 4 VGPR
typedef __attribute__((ext_vector_type(4))) float f32x4;

__device__ inline uint32_t f2bf(float f){
    uint32_t u = __float_as_uint(f);
    return (u + 0x7FFFu + ((u >> 16) & 1u)) >> 16;   // RNE bf16
}
__device__ inline float bflo(uint32_t u){ return __uint_as_float(u << 16); }
__device__ inline float bfhi(uint32_t u){ return __uint_as_float(u & 0xFFFF0000u); }
__device__ inline float bf1(short s){ return __uint_as_float(((uint32_t)(uint16_t)s) << 16); }

// ---------------- weight pre-pack into MFMA B-fragment order; zero bcnt ----------------
__global__ __launch_bounds__(256) void k_pack(const float* __restrict__ w1rel, const float* __restrict__ w1root,
                                              const float* __restrict__ w2rel, const float* __restrict__ w2root,
                                              short* __restrict__ wf, int* __restrict__ bcnt){
    int id = blockIdx.x * 256 + threadIdx.x;          // 65536 total
    if (id < NB) bcnt[id] = 0;
    int i = id & 7, lane = (id >> 3) & 63, ks = (id >> 9) & 3, j0 = (id >> 11) & 7, m = id >> 14;
    const float* W = (m == 0) ? w1rel : (m == 1) ? w1root : (m == 2) ? w2rel : w2root;
    int j = j0 * 16 + (lane & 15);
    int k = ks * 32 + (lane >> 4) * 8 + i;
    wf[id] = (short)f2bf(W[j * 128 + k]);
}

// ---------------- fused: embedding+max_norm | coarse hist | graph boundaries ----------------
__global__ __launch_bounds__(256) void k_embed(const int* __restrict__ x,
                                               const float* __restrict__ emb,
                                               uint32_t* __restrict__ hout,
                                               const int* __restrict__ edst,
                                               int* __restrict__ bcnt,
                                               const int* __restrict__ batch,
                                               int* __restrict__ gstart){
    int bid = blockIdx.x;
    if (bid < NN / 4){
        int w = threadIdx.x >> 6, l = threadIdx.x & 63;
        int n = bid * 4 + w;
        int r = x[n];
        const float2* e2 = (const float2*)emb;
        float2 v = e2[(size_t)r * 64 + l];
        float ss = v.x * v.x + v.y * v.y;
        #pragma unroll
        for (int off = 32; off; off >>= 1) ss += __shfl_xor(ss, off, 64);
        float sc = fminf(1.f, 1.f / (sqrtf(ss) + 1e-7f));
        hout[(size_t)n * 64 + l] = f2bf(v.x * sc) | (f2bf(v.y * sc) << 16);
    } else if (bid < NN / 4 + NCH){
        __shared__ int lh[NB];
        int t = threadIdx.x;
        int c0 = (bid - NN / 4) * CHUNK;
        int cnt = min(CHUNK, NE - c0);
        lh[t] = 0;
        if (t + 256 < NB) lh[t + 256] = 0;
        __syncthreads();
        for (int i = t; i < cnt; i += 256) atomicAdd(&lh[edst[c0 + i] >> 8], 1);
        __syncthreads();
        if (lh[t]) atomicAdd(&bcnt[t], lh[t]);
        if (t + 256 < NB && lh[t + 256]) atomicAdd(&bcnt[t + 256], lh[t + 256]);
    } else {
        int i = (bid - NN / 4 - NCH) * 256 + threadIdx.x;
        if (i > NN) return;
        int bprev = (i == 0) ? -1 : batch[i - 1];
        int bcur  = (i == NN) ? NG : batch[i];
        for (int g = bprev + 1; g <= bcur; ++g) gstart[g] = i;
    }
}

// ---------------- scan bucket counts -> bbase[NB+1]; zero bfill; ptrA[NN] = NE ----------------
__global__ __launch_bounds__(256) void k_bscan(const int* __restrict__ bcnt,
                                               int* __restrict__ bbase, int* __restrict__ bfill,
                                               int* __restrict__ ptrA){
    __shared__ int sc[512];
    int t = threadIdx.x;
    int v0 = (t < NB) ? bcnt[t] : 0;
    int v1 = (t + 256 < NB) ? bcnt[t + 256] : 0;
    sc[t] = v0; sc[t + 256] = v1;
    __syncthreads();
    for (int off = 1; off < 512; off <<= 1){
        int u0 = (t >= off) ? sc[t - off] : 0;
        int u1 = sc[t + 256 - off];
        __syncthreads();
        sc[t] += u0; sc[t + 256] += u1;
        __syncthreads();
    }
    if (t < NB){ bbase[t] = sc[t] - v0; bfill[t] = 0; }
    if (t + 256 < NB){ bbase[t + 256] = sc[t + 256] - v1; bfill[t + 256] = 0; }
    if (t == 0){ bbase[NB] = NE; ptrA[NN] = NE; }
}

// ---------------- chunk-local counting sort by bucket, contiguous global chunk writes ----------------
// record: x = src | (dst&255)<<20 , y = weight bits
__global__ __launch_bounds__(256) void k_bscatter(const int* __restrict__ esrc, const int* __restrict__ edst,
                                                  const float* __restrict__ ew,
                                                  const int* __restrict__ bbase, int* __restrict__ bfill,
                                                  uint2* __restrict__ cse2){
    __shared__ uint2 rec[CHUNK];
    __shared__ unsigned short slotb[CHUNK];
    __shared__ int hist[512], start[512], gbase[512], sc[512];
    int t = threadIdx.x;
    int c0 = blockIdx.x * CHUNK;
    int cnt = min(CHUNK, NE - c0);
    hist[t] = 0; hist[t + 256] = 0;
    __syncthreads();
    for (int i = t; i < cnt; i += 256) atomicAdd(&hist[edst[c0 + i] >> 8], 1);
    __syncthreads();
    int v0 = hist[t], v1 = hist[t + 256];
    sc[t] = v0; sc[t + 256] = v1;
    __syncthreads();
    for (int off = 1; off < 512; off <<= 1){
        int u0 = (t >= off) ? sc[t - off] : 0;
        int u1 = sc[t + 256 - off];
        __syncthreads();
        sc[t] += u0; sc[t + 256] += u1;
        __syncthreads();
    }
    start[t] = sc[t] - v0;
    start[t + 256] = sc[t + 256] - v1;
    if (t < NB && v0 > 0) gbase[t] = bbase[t] + atomicAdd(&bfill[t], v0);
    if (t + 256 < NB && v1 > 0) gbase[t + 256] = bbase[t + 256] + atomicAdd(&bfill[t + 256], v1);
    __syncthreads();
    hist[t] = 0; hist[t + 256] = 0;     // reuse as fill
    __syncthreads();
    for (int i = t; i < cnt; i += 256){
        int d = edst[c0 + i];
        int b = d >> 8;
        int slot = start[b] + atomicAdd(&hist[b], 1);
        rec[slot] = make_uint2((uint32_t)esrc[c0 + i] | ((uint32_t)(d & 255) << 20),
                               __float_as_uint(ew[c0 + i]));
        slotb[slot] = (unsigned short)b;
    }
    __syncthreads();
    for (int i = t; i < cnt; i += 256){
        int b = slotb[i];
        cse2[gbase[b] + (i - start[b])] = rec[i];
    }
}

// ---------------- per-bucket fine CSR (256 nodes); writes ptrA and final cse ----------------
// final record: x = (src byte-offset = src*256), y = weight bits
__global__ __launch_bounds__(256) void k_bcsr(const uint2* __restrict__ cse2,
                                              const int* __restrict__ bbase,
                                              int* __restrict__ ptrA,
                                              uint2* __restrict__ cse){
    __shared__ int cnt[256], sc[256], st[256];
    int t = threadIdx.x;
    int b = blockIdx.x;
    int ebase = bbase[b], eend = bbase[b + 1];
    int nb = b << 8;
    cnt[t] = 0;
    __syncthreads();
    for (int i = ebase + t; i < eend; i += 256){
        atomicAdd(&cnt[cse2[i].x >> 20], 1);
    }
    __syncthreads();
    int v = cnt[t];
    sc[t] = v;
    __syncthreads();
    for (int off = 1; off < 256; off <<= 1){
        int u = (t >= off) ? sc[t - off] : 0;
        __syncthreads();
        sc[t] += u;
        __syncthreads();
    }
    st[t] = sc[t] - v;
    if (nb + t < NN) ptrA[nb + t] = ebase + st[t];
    cnt[t] = 0;                          // reuse as fill
    __syncthreads();
    for (int i = ebase + t; i < eend; i += 256){
        uint2 r = cse2[i];
        int dr = r.x >> 20;
        int pos = st[dr] + atomicAdd(&cnt[dr], 1);
        cse[ebase + pos] = make_uint2((r.x & 0xFFFFFu) << 8, r.y);
    }
}

// ---------------- gather-aggregate: 4 rows per VMEM instr (quarter-wave per edge) ----------------
// wave = node; quarter q takes edge e+q; lane c (0..15) covers 8 bf16 cols via uint4
#define ACC8(vv, ww) \
    a0 += ww * bflo(vv.x); a1 += ww * bfhi(vv.x); \
    a2 += ww * bflo(vv.y); a3 += ww * bfhi(vv.y); \
    a4 += ww * bflo(vv.z); a5 += ww * bfhi(vv.z); \
    a6 += ww * bflo(vv.w); a7 += ww * bfhi(vv.w);

__global__ __launch_bounds__(256) void k_agg(const uint32_t* __restrict__ hin,
                                             uint32_t* __restrict__ aggo,
                                             const int* __restrict__ ptr,
                                             const uint2* __restrict__ cse){
    int w = threadIdx.x >> 6, l = threadIdx.x & 63;
    int q = l >> 4, c = l & 15;
    int n = blockIdx.x * 4 + w;
    int p0 = ptr[n], p1 = ptr[n + 1];
    const char* hb = (const char*)hin;
    uint32_t coff = (uint32_t)(c << 4);
    float a0 = 0, a1 = 0, a2 = 0, a3 = 0, a4 = 0, a5 = 0, a6 = 0, a7 = 0;
    int e = p0;
    for (; e + 16 <= p1; e += 16){
        uint2 r0 = cse[e + q], r1 = cse[e + 4 + q], r2 = cse[e + 8 + q], r3 = cse[e + 12 + q];
        uint4 v0 = *(const uint4*)(hb + (r0.x + coff));
        uint4 v1 = *(const uint4*)(hb + (r1.x + coff));
        uint4 v2 = *(const uint4*)(hb + (r2.x + coff));
        uint4 v3 = *(const uint4*)(hb + (r3.x + coff));
        float w0 = __uint_as_float(r0.y), w1 = __uint_as_float(r1.y);
        float w2 = __uint_as_float(r2.y), w3 = __uint_as_float(r3.y);
        ACC8(v0, w0); ACC8(v1, w1); ACC8(v2, w2); ACC8(v3, w3);
    }
    for (; e + 8 <= p1; e += 8){
        uint2 r0 = cse[e + q], r1 = cse[e + 4 + q];
        uint4 v0 = *(const uint4*)(hb + (r0.x + coff));
        uint4 v1 = *(const uint4*)(hb + (r1.x + coff));
        float w0 = __uint_as_float(r0.y), w1 = __uint_as_float(r1.y);
        ACC8(v0, w0); ACC8(v1, w1);
    }
    for (; e + 4 <= p1; e += 4){
        uint2 r0 = cse[e + q];
        uint4 v0 = *(const uint4*)(hb + (r0.x + coff));
        float w0 = __uint_as_float(r0.y);
        ACC8(v0, w0);
    }
    if (e < p1){                                  // 1..3 edges left (p1 > p0 here)
        int idx = e + q;
        int cidx = (idx < p1) ? idx : (p1 - 1);
        uint2 r0 = cse[cidx];
        uint4 v0 = *(const uint4*)(hb + (r0.x + coff));
        float w0 = (idx < p1) ? __uint_as_float(r0.y) : 0.f;
        ACC8(v0, w0);
    }
    // reduce across the 4 quarters (lanes c, 16+c, 32+c, 48+c)
    a0 += __shfl_xor(a0, 16, 64); a0 += __shfl_xor(a0, 32, 64);
    a1 += __shfl_xor(a1, 16, 64); a1 += __shfl_xor(a1, 32, 64);
    a2 += __shfl_xor(a2, 16, 64); a2 += __shfl_xor(a2, 32, 64);
    a3 += __shfl_xor(a3, 16, 64); a3 += __shfl_xor(a3, 32, 64);
    a4 += __shfl_xor(a4, 16, 64); a4 += __shfl_xor(a4, 32, 64);
    a5 += __shfl_xor(a5, 16, 64); a5 += __shfl_xor(a5, 32, 64);
    a6 += __shfl_xor(a6, 16, 64); a6 += __shfl_xor(a6, 32, 64);
    a7 += __shfl_xor(a7, 16, 64); a7 += __shfl_xor(a7, 32, 64);
    if (q == 0){
        uint4 o;
        o.x = f2bf(a0) | (f2bf(a1) << 16);
        o.y = f2bf(a2) | (f2bf(a3) << 16);
        o.z = f2bf(a4) | (f2bf(a5) << 16);
        o.w = f2bf(a6) | (f2bf(a7) << 16);
        *(uint4*)((char*)aggo + (size_t)n * 256 + coff) = o;
    }
}

// ---------------- MFMA GEMM: out = relu(bias + agg@Wrel^T + h@Wroot^T) ----------------
__global__ __launch_bounds__(256) void k_gemm(const short* __restrict__ hin,
                                              const short* __restrict__ agg,
                                              short* __restrict__ hout,
                                              const bf16x8* __restrict__ wrel,   // [8][4][64]
                                              const bf16x8* __restrict__ wroot,
                                              const float* __restrict__ bias){
    int t = threadIdx.x, w = t >> 6, l = t & 63;
    int rbase = blockIdx.x * 128 + w * 32;
    int r0 = rbase + (l & 15);
    int rA0 = min(r0, NN - 1);
    int rA1 = min(r0 + 16, NN - 1);
    int kb = (l >> 4) * 8;

    bf16x8 aA[2][4], aH[2][4];
    const short* pa0 = agg + (size_t)rA0 * 128 + kb;
    const short* pa1 = agg + (size_t)rA1 * 128 + kb;
    const short* ph0 = hin + (size_t)rA0 * 128 + kb;
    const short* ph1 = hin + (size_t)rA1 * 128 + kb;
    #pragma unroll
    for (int ks = 0; ks < 4; ++ks){
        aA[0][ks] = *(const bf16x8*)(pa0 + ks * 32);
        aA[1][ks] = *(const bf16x8*)(pa1 + ks * 32);
        aH[0][ks] = *(const bf16x8*)(ph0 + ks * 32);
        aH[1][ks] = *(const bf16x8*)(ph1 + ks * 32);
    }

    for (int j0 = 0; j0 < 8; ++j0){
        f32x4 acc0 = {0.f, 0.f, 0.f, 0.f}, acc1 = {0.f, 0.f, 0.f, 0.f};
        #pragma unroll
        for (int ks = 0; ks < 4; ++ks){
            bf16x8 br = wrel [(j0 * 4 + ks) * 64 + l];
            bf16x8 bo = wroot[(j0 * 4 + ks) * 64 + l];
            acc0 = __builtin_amdgcn_mfma_f32_16x16x32_bf16(aA[0][ks], br, acc0, 0, 0, 0);
            acc0 = __builtin_amdgcn_mfma_f32_16x16x32_bf16(aH[0][ks], bo, acc0, 0, 0, 0);
            acc1 = __builtin_amdgcn_mfma_f32_16x16x32_bf16(aA[1][ks], br, acc1, 0, 0, 0);
            acc1 = __builtin_amdgcn_mfma_f32_16x16x32_bf16(aH[1][ks], bo, acc1, 0, 0, 0);
        }
        int col = j0 * 16 + (l & 15);
        float bv = bias[col];
        int rb = rbase + (l >> 4) * 4;
        #pragma unroll
        for (int r = 0; r < 4; ++r){
            int row = rb + r;
            if (row < NN){
                float v = fmaxf(acc0[r] + bv, 0.f);
                hout[(size_t)row * 128 + col] = (short)f2bf(v);
            }
            int row1 = rb + 16 + r;
            if (row1 < NN){
                float v = fmaxf(acc1[r] + bv, 0.f);
                hout[(size_t)row1 * 128 + col] = (short)f2bf(v);
            }
        }
    }
}

// ---------------- fused mean-pool + classifier + softmax ----------------
__global__ __launch_bounds__(128) void k_poolcls(const short* __restrict__ h,
                                                 const int* __restrict__ gstart,
                                                 const float* __restrict__ c1w, const float* __restrict__ c1b,
                                                 const float* __restrict__ c2w, const float* __restrict__ c2b,
                                                 float* __restrict__ out){
    __shared__ float pl[128];
    __shared__ float z[64];
    __shared__ float logits[2];
    int g = blockIdx.x, t = threadIdx.x;
    int s = gstart[g], e = gstart[g + 1];
    float a0 = 0, a1 = 0, a2 = 0, a3 = 0;
    int i = s;
    for (; i + 3 < e; i += 4){
        a0 += bf1(h[(size_t)i * 128 + t]);
        a1 += bf1(h[(size_t)(i + 1) * 128 + t]);
        a2 += bf1(h[(size_t)(i + 2) * 128 + t]);
        a3 += bf1(h[(size_t)(i + 3) * 128 + t]);
    }
    for (; i < e; ++i) a0 += bf1(h[(size_t)i * 128 + t]);
    float sum = (a0 + a1) + (a2 + a3);
    int cnt = e - s;
    pl[t] = sum / fmaxf((float)cnt, 1.f);
    __syncthreads();
    if (t < 64){
        float acc = c1b[t];
        #pragma unroll 4
        for (int k = 0; k < 128; ++k) acc += pl[k] * c1w[t * 128 + k];
        z[t] = fmaxf(acc, 0.f);
    }
    __syncthreads();
    if (t < 2){
        float a = c2b[t];
        for (int k = 0; k < 64; ++k) a += z[k] * c2w[t * 64 + k];
        logits[t] = a;
    }
    __syncthreads();
    if (t == 0){
        float m = fmaxf(logits[0], logits[1]);
        float e0 = expf(logits[0] - m), e1 = expf(logits[1] - m);
        float ss = e0 + e1;
        out[g * 2 + 0] = e0 / ss;
        out[g * 2 + 1] = e1 / ss;
    }
}

extern "C" void kernel_launch(void* const* d_in, const int* in_sizes, int n_in,
                              void* d_out, int out_size, void* d_ws, size_t ws_size,
                              hipStream_t stream) {
    const int*   x      = (const int*)  d_in[0];
    const int*   eidx   = (const int*)  d_in[1];
    const float* ew     = (const float*)d_in[2];
    const int*   batch  = (const int*)  d_in[3];
    const float* emb    = (const float*)d_in[4];
    const float* w1rel  = (const float*)d_in[5];
    const float* b1     = (const float*)d_in[6];
    const float* w1root = (const float*)d_in[7];
    const float* w2rel  = (const float*)d_in[8];
    const float* b2     = (const float*)d_in[9];
    const float* w2root = (const float*)d_in[10];
    const float* c1w    = (const float*)d_in[11];
    const float* c1b    = (const float*)d_in[12];
    const float* c2w    = (const float*)d_in[13];
    const float* c2b    = (const float*)d_in[14];
    float* out = (float*)d_out;

    const int N = NN;                 // 100000
    const int E = NE;                 // 1600000

    char* p = (char*)d_ws;
    auto alloc = [&](size_t bytes) -> void* {
        void* r = (void*)p;
        p += (bytes + 255) & ~(size_t)255;
        return r;
    };
    uint32_t* hA   = (uint32_t*)alloc((size_t)N * 64 * 4);   // bf16x2 features
    uint32_t* hB   = (uint32_t*)alloc((size_t)N * 64 * 4);
    uint32_t* agg  = (uint32_t*)alloc((size_t)N * 64 * 4);
    int*   ptrA   = (int*)  alloc((size_t)(N + 1) * 4);
    int*   bcnt   = (int*)  alloc(NB * 4);
    int*   bbase  = (int*)  alloc((NB + 1) * 4);
    int*   bfill  = (int*)  alloc(NB * 4);
    uint2* cse2   = (uint2*)alloc((size_t)E * 8);
    uint2* cse    = (uint2*)alloc((size_t)E * 8);
    int*   gstart = (int*)  alloc((NG + 1) * 4);
    short* wf     = (short*)alloc(4 * 16384 * 2);
    (void)alloc(65536);               // safety pad for clamped OOB reads

    const bf16x8* wf1rel  = (const bf16x8*)(wf);
    const bf16x8* wf1root = (const bf16x8*)(wf + 16384);
    const bf16x8* wf2rel  = (const bf16x8*)(wf + 32768);
    const bf16x8* wf2root = (const bf16x8*)(wf + 49152);

    const int* esrc = eidx;
    const int* edst = eidx + E;

    k_pack <<<256, 256, 0, stream>>>(w1rel, w1root, w2rel, w2root, wf, bcnt);
    k_embed<<<N / 4 + NCH + NGS, 256, 0, stream>>>(x, emb, hA, edst, bcnt, batch, gstart);

    k_bscan   <<<1,   256, 0, stream>>>(bcnt, bbase, bfill, ptrA);
    k_bscatter<<<NCH, 256, 0, stream>>>(esrc, edst, ew, bbase, bfill, cse2);
    k_bcsr    <<<NB,  256, 0, stream>>>(cse2, bbase, ptrA, cse);

    int ngemm = (N + 127) / 128;      // 782
    k_agg <<<N / 4, 256, 0, stream>>>(hA, agg, ptrA, cse);
    k_gemm<<<ngemm, 256, 0, stream>>>((const short*)hA, (const short*)agg, (short*)hB,
                                      wf1rel, wf1root, b1);
    k_agg <<<N / 4, 256, 0, stream>>>(hB, agg, ptrA, cse);
    k_gemm<<<ngemm, 256, 0, stream>>>((const short*)hB, (const short*)agg, (short*)hA,
                                      wf2rel, wf2root, b2);

    k_poolcls<<<NG, 128, 0, stream>>>((const short*)hA, gstart, c1w, c1b, c2w, c2b, out);
}

// Round 7
// 361.977 us; speedup vs baseline: 3.4589x; 1.0018x over previous
//
#include <hip/hip_runtime.h>
#include <stdint.h>

// Sizes (fixed by problem)
#define NN 100000
#define NE 1600000
#define NG 256
#define NB 391          // buckets of 256 nodes: ceil(100000/256)
#define CHUNK 4096
#define NCH 391         // ceil(NE/CHUNK)
#define NGS 392         // gstart blocks: ceil((NN+1)/256)

typedef __attribute__((ext_vector_type(8))) short bf16x8;   // 8 bf16 = 4 VGPR
typedef __attribute__((ext_vector_type(4))) float f32x4;

__device__ inline uint32_t f2bf(float f){
    uint32_t u = __float_as_uint(f);
    return (u + 0x7FFFu + ((u >> 16) & 1u)) >> 16;   // RNE bf16
}
__device__ inline float bflo(uint32_t u){ return __uint_as_float(u << 16); }
__device__ inline float bfhi(uint32_t u){ return __uint_as_float(u & 0xFFFF0000u); }
__device__ inline float bf1(short s){ return __uint_as_float(((uint32_t)(uint16_t)s) << 16); }

// ---------------- fused: embedding+max_norm | coarse hist | graph boundaries | weight pack ----------------
__global__ __launch_bounds__(256) void k_embed(const int* __restrict__ x,
                                               const float* __restrict__ emb,
                                               uint32_t* __restrict__ hout,
                                               const int* __restrict__ edst,
                                               int* __restrict__ bcnt,
                                               const int* __restrict__ batch,
                                               int* __restrict__ gstart,
                                               const float* __restrict__ w1rel, const float* __restrict__ w1root,
                                               const float* __restrict__ w2rel, const float* __restrict__ w2root,
                                               short* __restrict__ wf){
    int bid = blockIdx.x;
    if (bid < NN / 4){
        int w = threadIdx.x >> 6, l = threadIdx.x & 63;
        int n = bid * 4 + w;
        int r = x[n];
        const float2* e2 = (const float2*)emb;
        float2 v = e2[(size_t)r * 64 + l];
        float ss = v.x * v.x + v.y * v.y;
        #pragma unroll
        for (int off = 32; off; off >>= 1) ss += __shfl_xor(ss, off, 64);
        float sc = fminf(1.f, 1.f / (sqrtf(ss) + 1e-7f));
        hout[(size_t)n * 64 + l] = f2bf(v.x * sc) | (f2bf(v.y * sc) << 16);
    } else if (bid < NN / 4 + NCH){
        __shared__ int lh[NB];
        int t = threadIdx.x;
        int c0 = (bid - NN / 4) * CHUNK;
        int cnt = min(CHUNK, NE - c0);
        lh[t] = 0;
        if (t + 256 < NB) lh[t + 256] = 0;
        __syncthreads();
        for (int i = t; i < cnt; i += 256) atomicAdd(&lh[edst[c0 + i] >> 8], 1);
        __syncthreads();
        if (lh[t]) atomicAdd(&bcnt[t], lh[t]);
        if (t + 256 < NB && lh[t + 256]) atomicAdd(&bcnt[t + 256], lh[t + 256]);
    } else if (bid < NN / 4 + NCH + NGS){
        int i = (bid - NN / 4 - NCH) * 256 + threadIdx.x;
        if (i > NN) return;
        int bprev = (i == 0) ? -1 : batch[i - 1];
        int bcur  = (i == NN) ? NG : batch[i];
        for (int g = bprev + 1; g <= bcur; ++g) gstart[g] = i;
    } else {
        int id = (bid - NN / 4 - NCH - NGS) * 256 + threadIdx.x;   // 65536 total
        int i = id & 7, lane = (id >> 3) & 63, ks = (id >> 9) & 3, j0 = (id >> 11) & 7, m = id >> 14;
        const float* W = (m == 0) ? w1rel : (m == 1) ? w1root : (m == 2) ? w2rel : w2root;
        int j = j0 * 16 + (lane & 15);
        int k = ks * 32 + (lane >> 4) * 8 + i;
        wf[id] = (short)f2bf(W[j * 128 + k]);
    }
}

// ---------------- chunk-local counting sort by bucket (scan of bcnt fused in) ----------------
// record: x = src | (dst&255)<<20 , y = weight bits
__global__ __launch_bounds__(256) void k_bscatter(const int* __restrict__ esrc, const int* __restrict__ edst,
                                                  const float* __restrict__ ew,
                                                  const int* __restrict__ bcnt,
                                                  int* __restrict__ bbase, int* __restrict__ bfill,
                                                  uint2* __restrict__ cse2, int* __restrict__ ptrA){
    __shared__ uint2 rec[CHUNK];            // 32 KB
    __shared__ unsigned short slotb[CHUNK]; // 8 KB
    __shared__ int bb[512], hist[512], start[512], gbase[512], sc[512]; // 10 KB
    int t = threadIdx.x;
    // global bucket-count scan -> bb (every block computes it; identical results)
    int g0 = (t < NB) ? bcnt[t] : 0;
    int g1 = (t + 256 < NB) ? bcnt[t + 256] : 0;
    sc[t] = g0; sc[t + 256] = g1;
    __syncthreads();
    for (int off = 1; off < 512; off <<= 1){
        int u0 = (t >= off) ? sc[t - off] : 0;
        int u1 = sc[t + 256 - off];
        __syncthreads();
        sc[t] += u0; sc[t + 256] += u1;
        __syncthreads();
    }
    bb[t] = sc[t] - g0; bb[t + 256] = sc[t + 256] - g1;
    if (t < NB) bbase[t] = bb[t];
    if (t + 256 < NB) bbase[t + 256] = bb[t + 256];
    if (t == 0){ bbase[NB] = NE; ptrA[NN] = NE; }
    // local chunk histogram
    hist[t] = 0; hist[t + 256] = 0;
    __syncthreads();
    int c0 = blockIdx.x * CHUNK;
    int cnt = min(CHUNK, NE - c0);
    for (int i = t; i < cnt; i += 256) atomicAdd(&hist[edst[c0 + i] >> 8], 1);
    __syncthreads();
    int v0 = hist[t], v1 = hist[t + 256];
    sc[t] = v0; sc[t + 256] = v1;
    __syncthreads();
    for (int off = 1; off < 512; off <<= 1){
        int u0 = (t >= off) ? sc[t - off] : 0;
        int u1 = sc[t + 256 - off];
        __syncthreads();
        sc[t] += u0; sc[t + 256] += u1;
        __syncthreads();
    }
    start[t] = sc[t] - v0;
    start[t + 256] = sc[t + 256] - v1;
    if (t < NB && v0 > 0) gbase[t] = bb[t] + atomicAdd(&bfill[t], v0);
    if (t + 256 < NB && v1 > 0) gbase[t + 256] = bb[t + 256] + atomicAdd(&bfill[t + 256], v1);
    __syncthreads();
    hist[t] = 0; hist[t + 256] = 0;     // reuse as fill
    __syncthreads();
    for (int i = t; i < cnt; i += 256){
        int d = edst[c0 + i];
        int b = d >> 8;
        int slot = start[b] + atomicAdd(&hist[b], 1);
        rec[slot] = make_uint2((uint32_t)esrc[c0 + i] | ((uint32_t)(d & 255) << 20),
                               __float_as_uint(ew[c0 + i]));
        slotb[slot] = (unsigned short)b;
    }
    __syncthreads();
    for (int i = t; i < cnt; i += 256){
        int b = slotb[i];
        cse2[gbase[b] + (i - start[b])] = rec[i];
    }
}

// ---------------- per-bucket fine CSR (256 nodes); writes ptrA and final cse ----------------
// final record: x = (src byte-offset = src*256), y = weight bits
__global__ __launch_bounds__(256) void k_bcsr(const uint2* __restrict__ cse2,
                                              const int* __restrict__ bbase,
                                              int* __restrict__ ptrA,
                                              uint2* __restrict__ cse){
    __shared__ int cnt[256], sc[256], st[256];
    int t = threadIdx.x;
    int b = blockIdx.x;
    int ebase = bbase[b], eend = bbase[b + 1];
    int nb = b << 8;
    cnt[t] = 0;
    __syncthreads();
    for (int i = ebase + t; i < eend; i += 256){
        atomicAdd(&cnt[cse2[i].x >> 20], 1);
    }
    __syncthreads();
    int v = cnt[t];
    sc[t] = v;
    __syncthreads();
    for (int off = 1; off < 256; off <<= 1){
        int u = (t >= off) ? sc[t - off] : 0;
        __syncthreads();
        sc[t] += u;
        __syncthreads();
    }
    st[t] = sc[t] - v;
    if (nb + t < NN) ptrA[nb + t] = ebase + st[t];
    cnt[t] = 0;                          // reuse as fill
    __syncthreads();
    for (int i = ebase + t; i < eend; i += 256){
        uint2 r = cse2[i];
        int dr = r.x >> 20;
        int pos = st[dr] + atomicAdd(&cnt[dr], 1);
        cse[ebase + pos] = make_uint2((r.x & 0xFFFFFu) << 8, r.y);
    }
}

// ---------------- gather-aggregate v3: register-prefetched edge records + shuffle broadcast ----------------
// wave = node; lane l prefetches record l of the node's (<=64) edges; per 4-edge quad,
// 2 ds_bpermute broadcast {offset, weight} to the quarter handling that edge.
#define ACC8(vv, ww) \
    a0 += ww * bflo(vv.x); a1 += ww * bfhi(vv.x); \
    a2 += ww * bflo(vv.y); a3 += ww * bfhi(vv.y); \
    a4 += ww * bflo(vv.z); a5 += ww * bfhi(vv.z); \
    a6 += ww * bflo(vv.w); a7 += ww * bfhi(vv.w);

__global__ __launch_bounds__(256) void k_agg(const uint32_t* __restrict__ hin,
                                             uint32_t* __restrict__ aggo,
                                             const int* __restrict__ ptr,
                                             const uint2* __restrict__ cse){
    int w = threadIdx.x >> 6, l = threadIdx.x & 63;
    int q = l >> 4, c = l & 15;
    int n = blockIdx.x * 4 + w;
    int p0 = ptr[n], p1 = ptr[n + 1];
    const char* hb = (const char*)hin;
    uint32_t coff = (uint32_t)(c << 4);
    float a0 = 0, a1 = 0, a2 = 0, a3 = 0, a4 = 0, a5 = 0, a6 = 0, a7 = 0;
    for (int base = p0; base < p1; base += 64){
        int m = p1 - base; if (m > 64) m = 64;
        int li = (l < m) ? l : (m - 1);
        uint2 rec = cse[base + li];                  // one coalesced load covers 64 edges
        int   myo = (int)rec.x;
        float myw = (l < m) ? __uint_as_float(rec.y) : 0.f;
        int e = 0;
        for (; e + 16 <= m; e += 16){
            int   o0 = __shfl(myo, e + q, 64);      float w0 = __shfl(myw, e + q, 64);
            int   o1 = __shfl(myo, e + 4 + q, 64);  float w1 = __shfl(myw, e + 4 + q, 64);
            int   o2 = __shfl(myo, e + 8 + q, 64);  float w2 = __shfl(myw, e + 8 + q, 64);
            int   o3 = __shfl(myo, e + 12 + q, 64); float w3 = __shfl(myw, e + 12 + q, 64);
            uint4 v0 = *(const uint4*)(hb + ((uint32_t)o0 + coff));
            uint4 v1 = *(const uint4*)(hb + ((uint32_t)o1 + coff));
            uint4 v2 = *(const uint4*)(hb + ((uint32_t)o2 + coff));
            uint4 v3 = *(const uint4*)(hb + ((uint32_t)o3 + coff));
            ACC8(v0, w0); ACC8(v1, w1); ACC8(v2, w2); ACC8(v3, w3);
        }
        for (; e < m; e += 4){                       // tail quads: weights auto-zero past m
            int   o0 = __shfl(myo, e + q, 64);
            float w0 = __shfl(myw, e + q, 64);
            uint4 v0 = *(const uint4*)(hb + ((uint32_t)o0 + coff));
            ACC8(v0, w0);
        }
    }
    // reduce across the 4 quarters (lanes c, 16+c, 32+c, 48+c)
    a0 += __shfl_xor(a0, 16, 64); a0 += __shfl_xor(a0, 32, 64);
    a1 += __shfl_xor(a1, 16, 64); a1 += __shfl_xor(a1, 32, 64);
    a2 += __shfl_xor(a2, 16, 64); a2 += __shfl_xor(a2, 32, 64);
    a3 += __shfl_xor(a3, 16, 64); a3 += __shfl_xor(a3, 32, 64);
    a4 += __shfl_xor(a4, 16, 64); a4 += __shfl_xor(a4, 32, 64);
    a5 += __shfl_xor(a5, 16, 64); a5 += __shfl_xor(a5, 32, 64);
    a6 += __shfl_xor(a6, 16, 64); a6 += __shfl_xor(a6, 32, 64);
    a7 += __shfl_xor(a7, 16, 64); a7 += __shfl_xor(a7, 32, 64);
    if (q == 0){
        uint4 o;
        o.x = f2bf(a0) | (f2bf(a1) << 16);
        o.y = f2bf(a2) | (f2bf(a3) << 16);
        o.z = f2bf(a4) | (f2bf(a5) << 16);
        o.w = f2bf(a6) | (f2bf(a7) << 16);
        *(uint4*)((char*)aggo + (size_t)n * 256 + coff) = o;
    }
}

// ---------------- MFMA GEMM: out = relu(bias + agg@Wrel^T + h@Wroot^T) ----------------
__global__ __launch_bounds__(256) void k_gemm(const short* __restrict__ hin,
                                              const short* __restrict__ agg,
                                              short* __restrict__ hout,
                                              const bf16x8* __restrict__ wrel,   // [8][4][64]
                                              const bf16x8* __restrict__ wroot,
                                              const float* __restrict__ bias){
    int t = threadIdx.x, w = t >> 6, l = t & 63;
    int rbase = blockIdx.x * 128 + w * 32;
    int r0 = rbase + (l & 15);
    int rA0 = min(r0, NN - 1);
    int rA1 = min(r0 + 16, NN - 1);
    int kb = (l >> 4) * 8;

    bf16x8 aA[2][4], aH[2][4];
    const short* pa0 = agg + (size_t)rA0 * 128 + kb;
    const short* pa1 = agg + (size_t)rA1 * 128 + kb;
    const short* ph0 = hin + (size_t)rA0 * 128 + kb;
    const short* ph1 = hin + (size_t)rA1 * 128 + kb;
    #pragma unroll
    for (int ks = 0; ks < 4; ++ks){
        aA[0][ks] = *(const bf16x8*)(pa0 + ks * 32);
        aA[1][ks] = *(const bf16x8*)(pa1 + ks * 32);
        aH[0][ks] = *(const bf16x8*)(ph0 + ks * 32);
        aH[1][ks] = *(const bf16x8*)(ph1 + ks * 32);
    }

    for (int j0 = 0; j0 < 8; ++j0){
        f32x4 acc0 = {0.f, 0.f, 0.f, 0.f}, acc1 = {0.f, 0.f, 0.f, 0.f};
        #pragma unroll
        for (int ks = 0; ks < 4; ++ks){
            bf16x8 br = wrel [(j0 * 4 + ks) * 64 + l];
            bf16x8 bo = wroot[(j0 * 4 + ks) * 64 + l];
            acc0 = __builtin_amdgcn_mfma_f32_16x16x32_bf16(aA[0][ks], br, acc0, 0, 0, 0);
            acc0 = __builtin_amdgcn_mfma_f32_16x16x32_bf16(aH[0][ks], bo, acc0, 0, 0, 0);
            acc1 = __builtin_amdgcn_mfma_f32_16x16x32_bf16(aA[1][ks], br, acc1, 0, 0, 0);
            acc1 = __builtin_amdgcn_mfma_f32_16x16x32_bf16(aH[1][ks], bo, acc1, 0, 0, 0);
        }
        int col = j0 * 16 + (l & 15);
        float bv = bias[col];
        int rb = rbase + (l >> 4) * 4;
        #pragma unroll
        for (int r = 0; r < 4; ++r){
            int row = rb + r;
            if (row < NN){
                float v = fmaxf(acc0[r] + bv, 0.f);
                hout[(size_t)row * 128 + col] = (short)f2bf(v);
            }
            int row1 = rb + 16 + r;
            if (row1 < NN){
                float v = fmaxf(acc1[r] + bv, 0.f);
                hout[(size_t)row1 * 128 + col] = (short)f2bf(v);
            }
        }
    }
}

// ---------------- fused mean-pool + classifier + softmax ----------------
__global__ __launch_bounds__(128) void k_poolcls(const short* __restrict__ h,
                                                 const int* __restrict__ gstart,
                                                 const float* __restrict__ c1w, const float* __restrict__ c1b,
                                                 const float* __restrict__ c2w, const float* __restrict__ c2b,
                                                 float* __restrict__ out){
    __shared__ float pl[128];
    __shared__ float z[64];
    __shared__ float logits[2];
    int g = blockIdx.x, t = threadIdx.x;
    int s = gstart[g], e = gstart[g + 1];
    float a0 = 0, a1 = 0, a2 = 0, a3 = 0;
    int i = s;
    for (; i + 3 < e; i += 4){
        a0 += bf1(h[(size_t)i * 128 + t]);
        a1 += bf1(h[(size_t)(i + 1) * 128 + t]);
        a2 += bf1(h[(size_t)(i + 2) * 128 + t]);
        a3 += bf1(h[(size_t)(i + 3) * 128 + t]);
    }
    for (; i < e; ++i) a0 += bf1(h[(size_t)i * 128 + t]);
    float sum = (a0 + a1) + (a2 + a3);
    int cnt = e - s;
    pl[t] = sum / fmaxf((float)cnt, 1.f);
    __syncthreads();
    if (t < 64){
        float acc = c1b[t];
        #pragma unroll 4
        for (int k = 0; k < 128; ++k) acc += pl[k] * c1w[t * 128 + k];
        z[t] = fmaxf(acc, 0.f);
    }
    __syncthreads();
    if (t < 2){
        float a = c2b[t];
        for (int k = 0; k < 64; ++k) a += z[k] * c2w[t * 64 + k];
        logits[t] = a;
    }
    __syncthreads();
    if (t == 0){
        float m = fmaxf(logits[0], logits[1]);
        float e0 = expf(logits[0] - m), e1 = expf(logits[1] - m);
        float ss = e0 + e1;
        out[g * 2 + 0] = e0 / ss;
        out[g * 2 + 1] = e1 / ss;
    }
}

extern "C" void kernel_launch(void* const* d_in, const int* in_sizes, int n_in,
                              void* d_out, int out_size, void* d_ws, size_t ws_size,
                              hipStream_t stream) {
    const int*   x      = (const int*)  d_in[0];
    const int*   eidx   = (const int*)  d_in[1];
    const float* ew     = (const float*)d_in[2];
    const int*   batch  = (const int*)  d_in[3];
    const float* emb    = (const float*)d_in[4];
    const float* w1rel  = (const float*)d_in[5];
    const float* b1     = (const float*)d_in[6];
    const float* w1root = (const float*)d_in[7];
    const float* w2rel  = (const float*)d_in[8];
    const float* b2     = (const float*)d_in[9];
    const float* w2root = (const float*)d_in[10];
    const float* c1w    = (const float*)d_in[11];
    const float* c1b    = (const float*)d_in[12];
    const float* c2w    = (const float*)d_in[13];
    const float* c2b    = (const float*)d_in[14];
    float* out = (float*)d_out;

    const int N = NN;                 // 100000
    const int E = NE;                 // 1600000

    char* p = (char*)d_ws;
    auto alloc = [&](size_t bytes) -> void* {
        void* r = (void*)p;
        p += (bytes + 255) & ~(size_t)255;
        return r;
    };
    uint32_t* hA   = (uint32_t*)alloc((size_t)N * 64 * 4);   // bf16x2 features
    uint32_t* hB   = (uint32_t*)alloc((size_t)N * 64 * 4);
    uint32_t* agg  = (uint32_t*)alloc((size_t)N * 64 * 4);
    int*   ptrA   = (int*)  alloc((size_t)(N + 1) * 4);
    int*   bcnt   = (int*)  alloc(NB * 4);
    int*   bbase  = (int*)  alloc((NB + 1) * 4);
    int*   bfill  = (int*)  alloc(NB * 4);
    uint2* cse2   = (uint2*)alloc((size_t)E * 8);
    uint2* cse    = (uint2*)alloc((size_t)E * 8);
    int*   gstart = (int*)  alloc((NG + 1) * 4);
    short* wf     = (short*)alloc(4 * 16384 * 2);
    (void)alloc(65536);               // safety pad for clamped OOB reads

    const bf16x8* wf1rel  = (const bf16x8*)(wf);
    const bf16x8* wf1root = (const bf16x8*)(wf + 16384);
    const bf16x8* wf2rel  = (const bf16x8*)(wf + 32768);
    const bf16x8* wf2root = (const bf16x8*)(wf + 49152);

    const int* esrc = eidx;
    const int* edst = eidx + E;

    hipMemsetAsync(bcnt,  0, NB * 4, stream);
    hipMemsetAsync(bfill, 0, NB * 4, stream);

    k_embed<<<N / 4 + NCH + NGS + 256, 256, 0, stream>>>(x, emb, hA, edst, bcnt, batch, gstart,
                                                         w1rel, w1root, w2rel, w2root, wf);

    k_bscatter<<<NCH, 256, 0, stream>>>(esrc, edst, ew, bcnt, bbase, bfill, cse2, ptrA);
    k_bcsr    <<<NB,  256, 0, stream>>>(cse2, bbase, ptrA, cse);

    int ngemm = (N + 127) / 128;      // 782
    k_agg <<<N / 4, 256, 0, stream>>>(hA, agg, ptrA, cse);
    k_gemm<<<ngemm, 256, 0, stream>>>((const short*)hA, (const short*)agg, (short*)hB,
                                      wf1rel, wf1root, b1);
    k_agg <<<N / 4, 256, 0, stream>>>(hB, agg, ptrA, cse);
    k_gemm<<<ngemm, 256, 0, stream>>>((const short*)hB, (const short*)agg, (short*)hA,
                                      wf2rel, wf2root, b2);

    k_poolcls<<<NG, 128, 0, stream>>>((const short*)hA, gstart, c1w, c1b, c2w, c2b, out);
}